// Round 4
// baseline (1497.205 us; speedup 1.0000x reference)
//
#include <hip/hip_runtime.h>

#define EPSF 1e-5f

using short8  = __attribute__((ext_vector_type(8))) short;
using float4v = __attribute__((ext_vector_type(4))) float;

__device__ __forceinline__ unsigned short f2bf(float f){
    unsigned u = __float_as_uint(f);
    unsigned r = u + 0x7FFFu + ((u >> 16) & 1u);
    return (unsigned short)(r >> 16);
}
__device__ __forceinline__ float bf2f(unsigned short h){
    return __uint_as_float(((unsigned)h) << 16);
}
// monotone map: ascending float (incl. negatives) -> ascending uint
__device__ __forceinline__ unsigned monou(float f){
    unsigned u = __float_as_uint(f);
    return u ^ (((unsigned)((int)u >> 31)) | 0x80000000u);
}

// ---------------- point_cbr stage ----------------

__global__ __launch_bounds__(256) void pc1_kernel(const float* __restrict__ x,
                                                  const float* __restrict__ w1,
                                                  float* __restrict__ y){
    __shared__ float w[192];
    int t = threadIdx.x;
    if (t < 192) w[t] = w1[t];
    __syncthreads();
    int gid = blockIdx.x * 256 + t;       // over B*N
    int b = gid >> 12;
    int n = gid & 4095;
    const float* xb = x + (size_t)b * 3 * 4096;
    float x0 = xb[n], x1 = xb[4096 + n], x2 = xb[8192 + n];
    float* yb = y + (size_t)b * 64 * 4096;
    #pragma unroll
    for (int o = 0; o < 64; o++){
        float v = x0 * w[o*3] + x1 * w[o*3+1] + x2 * w[o*3+2];
        yb[(size_t)o * 4096 + n] = v;
    }
}

template<int C, int NN>
__global__ __launch_bounds__(256) void stats_bcn_kernel(const float* __restrict__ y,
                                                        float* __restrict__ sums){
    int blk = blockIdx.x;                  // b*C + c
    int c = blk % C;
    const float* p = y + (size_t)blk * NN;
    float s = 0.f, q = 0.f;
    for (int i = threadIdx.x; i < NN; i += 256){ float v = p[i]; s += v; q += v*v; }
    for (int o = 32; o > 0; o >>= 1){ s += __shfl_down(s, o, 64); q += __shfl_down(q, o, 64); }
    __shared__ float ls[4], lq[4];
    int w = threadIdx.x >> 6;
    if ((threadIdx.x & 63) == 0){ ls[w] = s; lq[w] = q; }
    __syncthreads();
    if (threadIdx.x == 0){
        s = ls[0] + ls[1] + ls[2] + ls[3];
        q = lq[0] + lq[1] + lq[2] + lq[3];
        atomicAdd(&sums[c], s);
        atomicAdd(&sums[C + c], q);
    }
}

__global__ void bn_finalize_kernel(const float* __restrict__ sums,
                                   const float* __restrict__ g,
                                   const float* __restrict__ bb,
                                   float* __restrict__ ss, int C, float invCnt){
    int c = blockIdx.x * blockDim.x + threadIdx.x;
    if (c < C){
        float m = sums[c] * invCnt;
        float v = sums[C + c] * invCnt - m * m;
        float sc = g[c] / sqrtf(v + EPSF);
        ss[c] = sc;
        ss[C + c] = bb[c] - m * sc;
    }
}

__global__ __launch_bounds__(256) void pc2_kernel(const float* __restrict__ y1,
                                                  const float* __restrict__ w2,
                                                  const float* __restrict__ ss,
                                                  float* __restrict__ y2){
    __shared__ float wt[64*64];   // wt[c*64+o] = w2[o*64+c]
    __shared__ float lss[128];
    int t = threadIdx.x;
    for (int i = t; i < 4096; i += 256){ int o = i & 63, c = i >> 6; wt[c*64+o] = w2[o*64+c]; }
    if (t < 128) lss[t] = ss[t];
    __syncthreads();
    int gid = blockIdx.x * 256 + t;
    int b = gid >> 12, n = gid & 4095;
    const float* yb = y1 + (size_t)b * 64 * 4096;
    float acc[64];
    #pragma unroll
    for (int o = 0; o < 64; o++) acc[o] = 0.f;
    for (int c = 0; c < 64; c++){
        float v = yb[(size_t)c * 4096 + n];
        v = fmaxf(v * lss[c] + lss[64 + c], 0.f);
        #pragma unroll
        for (int o = 0; o < 64; o++) acc[o] += v * wt[c*64 + o];
    }
    float* ob = y2 + (size_t)b * 64 * 4096;
    #pragma unroll
    for (int o = 0; o < 64; o++) ob[(size_t)o * 4096 + n] = acc[o];
}

// y2 (B,64,N) --bn+relu--> f (B,N,64)
__global__ __launch_bounds__(256) void transpose_f_kernel(const float* __restrict__ y2,
                                                          const float* __restrict__ ss,
                                                          float* __restrict__ f){
    __shared__ float tile[64][65];
    __shared__ float lss[128];
    int t = threadIdx.x;
    if (t < 128) lss[t] = ss[t];
    __syncthreads();
    int blk = blockIdx.x;               // b*(N/64) + ntile
    int b = blk >> 6;
    int nb = (blk & 63) * 64;
    const float* yb = y2 + (size_t)b * 64 * 4096;
    #pragma unroll
    for (int r = 0; r < 16; r++){
        int c = r * 4 + (t >> 6);
        int n = t & 63;
        float v = yb[(size_t)c * 4096 + nb + n];
        tile[c][n] = fmaxf(v * lss[c] + lss[64 + c], 0.f);
    }
    __syncthreads();
    float* fb = f + (size_t)b * 4096 * 64;
    #pragma unroll
    for (int r = 0; r < 16; r++){
        int n = r * 4 + (t >> 6);
        int c = t & 63;
        fb[(size_t)(nb + n) * 64 + c] = tile[c][n];
    }
}

// ---------------- FPS (latency-optimized, no global I/O in the loop) ----------------
// One workgroup per batch. TPB=256 => 4 waves = 1 wave/SIMD (more waves measured
// slower: R3 TPB=512 was 579us vs R2 TPB=256 404us — barrier skew + slot scan).
// Per iteration: dist P-loop -> packed u64 butterfly -> winner coords shfl ->
// (W>1: one barrier + slot tree). Outputs recorded to LDS hist, written back at end.
template<int NP, int SO, int TPB, bool STRIDED>
__global__ __launch_bounds__(TPB) void fps_kernel(const float* __restrict__ coords,
                                                  int* __restrict__ fidx,
                                                  float* __restrict__ xyz_out){
    __shared__ float lx[NP], ly[NP], lz[NP];
    __shared__ int hist[SO];
    constexpr int W = TPB / 64;
    __shared__ unsigned long long redk[2][W];
    __shared__ float redc[2][W][3];
    const int b = blockIdx.x, t = threadIdx.x;
    constexpr int P = NP / TPB;
    const float* cb = coords + (size_t)b * 3 * NP;
    float px[P], py[P], pz[P], dist[P];
    #pragma unroll
    for (int i = 0; i < P; i++){
        int n = i * TPB + t;
        float X, Y, Z;
        if (STRIDED){ X = cb[n]; Y = cb[NP + n]; Z = cb[2*NP + n]; }
        else        { X = cb[n*3]; Y = cb[n*3+1]; Z = cb[n*3+2]; }
        lx[n] = X; ly[n] = Y; lz[n] = Z;
        px[i] = X; py[i] = Y; pz[i] = Z;
        dist[i] = 1e10f;
    }
    __syncthreads();
    int cur = 0;
    float cx = lx[0], cy = ly[0], cz = lz[0];
    for (int it = 0; it < SO; ++it){
        if (t == 0) hist[it] = cur;
        float bd = -1.f, bx = 0.f, by = 0.f, bz = 0.f;
        int bn = 0;
        {
            #pragma clang fp contract(off)
            #pragma unroll
            for (int i = 0; i < P; i++){
                float dx = px[i] - cx, dy = py[i] - cy, dz = pz[i] - cz;
                float d = (dx*dx + dy*dy) + dz*dz;   // match np: no fma, ((x+y)+z)
                float nd = fminf(dist[i], d);
                dist[i] = nd;
                int n = i * TPB + t;
                if (nd > bd){ bd = nd; bn = n; bx = px[i]; by = py[i]; bz = pz[i]; }
            }
        }
        // bd >= 0 so raw float bits order correctly as uint
        unsigned long long key = ((unsigned long long)__float_as_uint(bd) << 32)
                               | (unsigned)(0xFFFFFFFFu - (unsigned)bn);
        #pragma unroll
        for (int o = 32; o > 0; o >>= 1){
            unsigned long long v = __shfl_xor(key, o, 64);
            key = key > v ? key : v;
        }
        int bnw = (int)(0xFFFFFFFFu - (unsigned)(key & 0xFFFFFFFFull));
        int owner = bnw & 63;
        float wx = __shfl(bx, owner, 64);
        float wy = __shfl(by, owner, 64);
        float wz = __shfl(bz, owner, 64);
        if constexpr (W == 1){
            cur = bnw; cx = wx; cy = wy; cz = wz;
        } else {
            int par = it & 1;
            if ((t & 63) == 0){
                int wv = t >> 6;
                redk[par][wv] = key;
                redc[par][wv][0] = wx; redc[par][wv][1] = wy; redc[par][wv][2] = wz;
            }
            __syncthreads();
            unsigned long long m = redk[par][0];
            float mx = redc[par][0][0], my = redc[par][0][1], mz = redc[par][0][2];
            #pragma unroll
            for (int j = 1; j < W; j++){
                unsigned long long v = redk[par][j];
                if (v > m){ m = v; mx = redc[par][j][0]; my = redc[par][j][1]; mz = redc[par][j][2]; }
            }
            cur = (int)(0xFFFFFFFFu - (unsigned)(m & 0xFFFFFFFFull));
            cx = mx; cy = my; cz = mz;
        }
    }
    __syncthreads();
    for (int i = t; i < SO; i += TPB){
        int h = hist[i];
        fidx[b * SO + i] = h;
        float* xo = xyz_out + ((size_t)b * SO + i) * 3;
        xo[0] = lx[h]; xo[1] = ly[h]; xo[2] = lz[h];
    }
}

// ---------------- kNN (exact top-32 by (dist, idx)) ----------------

template<int NC, int SO, bool STRIDED>
__global__ __launch_bounds__(64) void knn_kernel(const float* __restrict__ coords,
                                                 const float* __restrict__ samp,
                                                 int* __restrict__ knno){
    const int blk = blockIdx.x;
    const int b = blk / SO, s = blk % SO;
    const int lane = threadIdx.x;
    const float* cb = coords + (size_t)b * 3 * NC;
    const float* a = samp + ((size_t)b * SO + s) * 3;
    float ax = a[0], ay = a[1], az = a[2];
    float asq = ax*ax + ay*ay + az*az;
    constexpr int J = NC / 64;
    unsigned long long t8[8];
    #pragma unroll
    for (int i = 0; i < 8; i++) t8[i] = ~0ULL;
    for (int j = 0; j < J; j++){
        int n = j * 64 + lane;
        float bx, by, bz;
        if (STRIDED){ bx = cb[n]; by = cb[NC + n]; bz = cb[2*NC + n]; }
        else        { bx = cb[n*3]; by = cb[n*3+1]; bz = cb[n*3+2]; }
        float bsq = bx*bx + by*by + bz*bz;
        float dot = ax*bx + ay*by + az*bz;
        float d = (asq + bsq) - 2.0f * dot;       // reference's formula
        unsigned long long key = ((unsigned long long)monou(d) << 32) | (unsigned)n;
        if (key < t8[7]){
            t8[7] = key;
            #pragma unroll
            for (int i = 6; i >= 0; i--){
                if (t8[i] > t8[i+1]){ unsigned long long tm = t8[i]; t8[i] = t8[i+1]; t8[i+1] = tm; }
            }
        }
    }
    unsigned long long cur = t8[0];
    int myout = 0;
    bool bad = false;
    int popped = 0;
    for (int r = 0; r < 32; r++){
        unsigned long long m = cur;
        #pragma unroll
        for (int o2 = 32; o2 > 0; o2 >>= 1){
            unsigned long long v = __shfl_xor(m, o2, 64);
            m = m < v ? m : v;
        }
        if (lane == r) myout = (int)(unsigned)(m & 0xFFFFFFFFull);
        if (cur == m){
            #pragma unroll
            for (int i = 0; i < 7; i++) t8[i] = t8[i+1];
            t8[7] = ~0ULL;
            cur = t8[0];
            popped++;
            if (J > 8 && popped == 8 && r < 31) bad = true;
        }
    }
    if (__any(bad)){
        // exact fallback: ascending total-order scan (keys are unique)
        unsigned long long last = 0;
        for (int r = 0; r < 32; r++){
            unsigned long long mk = ~0ULL;
            for (int j = 0; j < J; j++){
                int n = j * 64 + lane;
                float bx, by, bz;
                if (STRIDED){ bx = cb[n]; by = cb[NC + n]; bz = cb[2*NC + n]; }
                else        { bx = cb[n*3]; by = cb[n*3+1]; bz = cb[n*3+2]; }
                float bsq = bx*bx + by*by + bz*bz;
                float dot = ax*bx + ay*by + az*bz;
                float d = (asq + bsq) - 2.0f * dot;
                unsigned long long key = ((unsigned long long)monou(d) << 32) | (unsigned)n;
                if (key > last && key < mk) mk = key;
            }
            unsigned long long m = mk;
            #pragma unroll
            for (int o2 = 32; o2 > 0; o2 >>= 1){
                unsigned long long v = __shfl_xor(m, o2, 64);
                m = m < v ? m : v;
            }
            if (lane == r) myout = (int)(unsigned)(m & 0xFFFFFFFFull);
            last = m;
        }
    }
    if (lane < 32) knno[((size_t)b * SO + s) * 32 + lane] = myout;
}

// ---------------- MFMA grouped MLP ----------------

template<int O, int D>
__global__ __launch_bounds__(256) void pack_w_kernel(const float* __restrict__ w,
                                                     unsigned short* __restrict__ pk){
    int tid = blockIdx.x * 256 + threadIdx.x;
    constexpr int CH = D / 32;
    constexpr int TOT = (O/16) * CH * 64;
    if (tid >= TOT) return;
    int lane = tid & 63;
    int fc = tid >> 6;
    int ch = fc % CH;
    int ot = fc / CH;
    int o  = ot * 16 + (lane & 15);
    int kb = ch * 32 + (lane >> 4) * 8;
    #pragma unroll
    for (int j = 0; j < 8; j++) pk[(size_t)tid * 8 + j] = f2bf(w[(size_t)o * D + kb + j]);
}

template<int D, int O>
__device__ __forceinline__ void mfma_compute_store(const short* A, const short* wp,
                                                   unsigned short* Y, float* lsum, float* lsq,
                                                   int blk, int t){
    constexpr int RS = D + 8;
    constexpr int CH = D / 32;
    constexpr int OT = O / 16;
    constexpr int OPW = OT / 4;
    int lane = t & 63, wv = t >> 6;
    int col = lane & 15, quad = lane >> 4;
    for (int oi = 0; oi < OPW; ++oi){
        int ot = wv * OPW + oi;
        for (int mt = 0; mt < 4; ++mt){
            float4v acc = {0.f, 0.f, 0.f, 0.f};
            #pragma unroll
            for (int ch = 0; ch < CH; ++ch){
                short8 a  = *(const short8*)(A + (mt*16 + col) * RS + ch*32 + quad*8);
                short8 bf = *(const short8*)(wp + ((size_t)(ot*CH + ch) * 64 + lane) * 8);
                acc = __builtin_amdgcn_mfma_f32_16x16x32_bf16(a, bf, acc, 0, 0, 0);
            }
            float s4 = 0.f, q4 = 0.f;
            size_t rowbase = (size_t)blk * 64 + mt * 16 + quad * 4;
            #pragma unroll
            for (int r = 0; r < 4; r++){
                float v = acc[r];
                s4 += v; q4 += v * v;
                Y[(rowbase + r) * O + ot * 16 + col] = f2bf(v);
            }
            s4 += __shfl_xor(s4, 16, 64); s4 += __shfl_xor(s4, 32, 64);
            q4 += __shfl_xor(q4, 16, 64); q4 += __shfl_xor(q4, 32, 64);
            if (quad == 0){ lsum[ot*16 + col] += s4; lsq[ot*16 + col] += q4; }
        }
    }
}

// layer1: gather + [f_nb - f_c | f_c] -> bf16 LDS -> MFMA, store Y bf16 + stats
template<int DH, int O, int S, int NPTS>
__global__ __launch_bounds__(256) void gemm1_kernel(const float* __restrict__ fsrc,
                                                    const int* __restrict__ fidx,
                                                    const int* __restrict__ knn,
                                                    const short* __restrict__ wp,
                                                    unsigned short* __restrict__ Y,
                                                    float* __restrict__ sums){
    constexpr int D = 2 * DH;
    constexpr int RS = D + 8;
    __shared__ __align__(16) short A[64 * RS];
    __shared__ float lsum[O], lsq[O];
    int t = threadIdx.x;
    for (int i = t; i < O; i += 256){ lsum[i] = 0.f; lsq[i] = 0.f; }
    int blk = blockIdx.x;
    for (int g = 0; g < 2; ++g){
        int gid = blk * 2 + g;
        int b = gid / S;
        int cidx = fidx[gid];
        const float* fc = fsrc + ((size_t)b * NPTS + cidx) * DH;
        int kk = t >> 3;
        int p  = t & 7;
        int nb = knn[(size_t)gid * 32 + kk];
        const float* fn = fsrc + ((size_t)b * NPTS + nb) * DH;
        constexpr int E = D / 8;
        int d0 = p * E;
        short* row = A + (g * 32 + kk) * RS;
        #pragma unroll
        for (int e = 0; e < E; e++){
            int d = d0 + e;
            float v = (d < DH) ? (fn[d] - fc[d]) : fc[d - DH];
            row[d] = (short)f2bf(v);
        }
    }
    __syncthreads();
    mfma_compute_store<D, O>(A, wp, Y, lsum, lsq, blk, t);
    __syncthreads();
    for (int i = t; i < O; i += 256){
        atomicAdd(&sums[i], lsum[i]);
        atomicAdd(&sums[O + i], lsq[i]);
    }
}

// layer2: bn+relu(Yin) -> bf16 LDS -> MFMA, store Y bf16 + stats
template<int D, int O>
__global__ __launch_bounds__(256) void gemm2_kernel(const unsigned short* __restrict__ Yin,
                                                    const float* __restrict__ ss,
                                                    const short* __restrict__ wp,
                                                    unsigned short* __restrict__ Y,
                                                    float* __restrict__ sums){
    constexpr int RS = D + 8;
    __shared__ __align__(16) short A[64 * RS];
    __shared__ float lsum[O], lsq[O];
    __shared__ float lss[2 * D];
    int t = threadIdx.x;
    for (int i = t; i < O; i += 256){ lsum[i] = 0.f; lsq[i] = 0.f; }
    for (int i = t; i < 2*D; i += 256) lss[i] = ss[i];
    __syncthreads();
    int blk = blockIdx.x;
    {
        int row = t >> 2;
        int d0 = (t & 3) * (D / 4);
        const unsigned short* src = Yin + ((size_t)blk * 64 + row) * D + d0;
        short* dst = A + row * RS + d0;
        #pragma unroll
        for (int e = 0; e < D/4; e++){
            float v = bf2f(src[e]);
            int d = d0 + e;
            v = fmaxf(v * lss[d] + lss[D + d], 0.f);
            dst[e] = (short)f2bf(v);
        }
    }
    __syncthreads();
    mfma_compute_store<D, O>(A, wp, Y, lsum, lsq, blk, t);
    __syncthreads();
    for (int i = t; i < O; i += 256){
        atomicAdd(&sums[i], lsum[i]);
        atomicAdd(&sums[O + i], lsq[i]);
    }
}

template<int O>
__global__ __launch_bounds__(256) void maxk_kernel(const unsigned short* __restrict__ Y,
                                                   const float* __restrict__ ss,
                                                   float* __restrict__ out){
    int gid = blockIdx.x * 256 + threadIdx.x;
    int o = gid % O;
    int r = gid / O;
    float sc = ss[o], sh = ss[O + o];
    const unsigned short* p = Y + (size_t)r * 32 * O + o;
    float m = -1e30f;
    #pragma unroll 8
    for (int k = 0; k < 32; k++){
        float v = bf2f(p[(size_t)k * O]);
        m = fmaxf(m, v * sc + sh);
    }
    out[gid] = fmaxf(m, 0.f);
}

// (B,256s,256o) -> (B,256o,256s)
__global__ __launch_bounds__(256) void transpose_out_kernel(const float* __restrict__ in,
                                                            float* __restrict__ out){
    __shared__ float tile[64][65];
    int blk = blockIdx.x;
    int b = blk >> 4;
    int ot = (blk >> 2) & 3, st = blk & 3;
    int t = threadIdx.x;
    const float* ib = in + (size_t)b * 65536;
    float* ob = out + (size_t)b * 65536;
    #pragma unroll
    for (int r = 0; r < 16; r++){
        int srow = st * 64 + r * 4 + (t >> 6);
        int o = ot * 64 + (t & 63);
        tile[r * 4 + (t >> 6)][t & 63] = ib[srow * 256 + o];
    }
    __syncthreads();
    #pragma unroll
    for (int r = 0; r < 16; r++){
        int o = ot * 64 + r * 4 + (t >> 6);
        int srow = st * 64 + (t & 63);
        ob[o * 256 + srow] = tile[t & 63][r * 4 + (t >> 6)];
    }
}

extern "C" void kernel_launch(void* const* d_in, const int* in_sizes, int n_in,
                              void* d_out, int out_size, void* d_ws, size_t ws_size,
                              hipStream_t stream) {
    const float* x    = (const float*)d_in[0];
    const float* w1   = (const float*)d_in[1];
    const float* w2   = (const float*)d_in[2];
    const float* g1   = (const float*)d_in[3];
    const float* b1   = (const float*)d_in[4];
    const float* g2   = (const float*)d_in[5];
    const float* b2   = (const float*)d_in[6];
    const float* s1w1 = (const float*)d_in[7];
    const float* s1w2 = (const float*)d_in[8];
    const float* s1g1 = (const float*)d_in[9];
    const float* s1b1 = (const float*)d_in[10];
    const float* s1g2 = (const float*)d_in[11];
    const float* s1b2 = (const float*)d_in[12];
    const float* s2w1 = (const float*)d_in[13];
    const float* s2w2 = (const float*)d_in[14];
    const float* s2g1 = (const float*)d_in[15];
    const float* s2b1 = (const float*)d_in[16];
    const float* s2g2 = (const float*)d_in[17];
    const float* s2b2 = (const float*)d_in[18];
    float* out = (float*)d_out;

    char* ws = (char*)d_ws;
    size_t off = 0;
    auto take = [&](size_t bytes){ size_t r = off; off += (bytes + 255) & ~(size_t)255; return r; };
    float* f_buf   = (float*)(ws + take(16u*4096u*64u*4u));      // f (B,N,64)
    float* f1_buf  = (float*)(ws + take(16u*512u*128u*4u));      // f1 (B,S1,128)
    int*   fidx1   = (int*)  (ws + take(16u*512u*4u));
    float* xyz1    = (float*)(ws + take(16u*512u*3u*4u));
    int*   fidx2   = (int*)  (ws + take(16u*256u*4u));
    float* xyz2    = (float*)(ws + take(16u*256u*3u*4u));
    int*   knn1    = (int*)  (ws + take(16u*512u*32u*4u));
    int*   knn2    = (int*)  (ws + take(16u*256u*32u*4u));
    unsigned short* wp1 = (unsigned short*)(ws + take(128u*128u*2u));
    unsigned short* wp2 = (unsigned short*)(ws + take(128u*128u*2u));
    unsigned short* wp3 = (unsigned short*)(ws + take(256u*256u*2u));
    unsigned short* wp4 = (unsigned short*)(ws + take(256u*256u*2u));
    float* stats   = (float*)(ws + take(6u*1024u*4u));
    float* ssb     = (float*)(ws + take(6u*1024u*4u));
    float* f2tmp   = (float*)(ws + take(16u*256u*256u*4u));
    char*  regA    = ws + take(67108864u);
    char*  regB    = ws + take(67108864u);
    (void)in_sizes; (void)n_in; (void)out_size; (void)ws_size;

    hipMemsetAsync(stats, 0, 6u*1024u*4u, stream);

    pack_w_kernel<128,128><<<8, 256, 0, stream>>>(s1w1, wp1);
    pack_w_kernel<128,128><<<8, 256, 0, stream>>>(s1w2, wp2);
    pack_w_kernel<256,256><<<32, 256, 0, stream>>>(s2w1, wp3);
    pack_w_kernel<256,256><<<32, 256, 0, stream>>>(s2w2, wp4);

    float* yA = (float*)regA;
    float* yB = (float*)regB;
    pc1_kernel<<<256, 256, 0, stream>>>(x, w1, yA);
    stats_bcn_kernel<64,4096><<<1024, 256, 0, stream>>>(yA, stats + 0*1024);
    bn_finalize_kernel<<<1, 256, 0, stream>>>(stats + 0*1024, g1, b1, ssb + 0*1024, 64, 1.f/65536.f);
    pc2_kernel<<<256, 256, 0, stream>>>(yA, w2, ssb + 0*1024, yB);
    stats_bcn_kernel<64,4096><<<1024, 256, 0, stream>>>(yB, stats + 1*1024);
    bn_finalize_kernel<<<1, 256, 0, stream>>>(stats + 1*1024, g2, b2, ssb + 1*1024, 64, 1.f/65536.f);
    transpose_f_kernel<<<1024, 256, 0, stream>>>(yB, ssb + 1*1024, f_buf);

    fps_kernel<4096,512,256,true><<<16, 256, 0, stream>>>(x, fidx1, xyz1);
    knn_kernel<4096,512,true><<<8192, 64, 0, stream>>>(x, xyz1, knn1);

    unsigned short* Y1 = (unsigned short*)regA;
    unsigned short* Y2 = (unsigned short*)regB;
    gemm1_kernel<64,128,512,4096><<<4096, 256, 0, stream>>>(f_buf, fidx1, knn1, (const short*)wp1, Y1, stats + 2*1024);
    bn_finalize_kernel<<<1, 256, 0, stream>>>(stats + 2*1024, s1g1, s1b1, ssb + 2*1024, 128, 1.f/262144.f);
    gemm2_kernel<128,128><<<4096, 256, 0, stream>>>(Y1, ssb + 2*1024, (const short*)wp2, Y2, stats + 3*1024);
    bn_finalize_kernel<<<1, 256, 0, stream>>>(stats + 3*1024, s1g2, s1b2, ssb + 3*1024, 128, 1.f/262144.f);
    maxk_kernel<128><<<4096, 256, 0, stream>>>(Y2, ssb + 3*1024, f1_buf);

    fps_kernel<512,256,64,false><<<16, 64, 0, stream>>>(xyz1, fidx2, xyz2);
    knn_kernel<512,256,false><<<4096, 64, 0, stream>>>(xyz1, xyz2, knn2);

    gemm1_kernel<128,256,256,512><<<2048, 256, 0, stream>>>(f1_buf, fidx2, knn2, (const short*)wp3, Y1, stats + 4*1024);
    bn_finalize_kernel<<<1, 256, 0, stream>>>(stats + 4*1024, s2g1, s2b1, ssb + 4*1024, 256, 1.f/131072.f);
    gemm2_kernel<256,256><<<2048, 256, 0, stream>>>(Y1, ssb + 4*1024, (const short*)wp4, Y2, stats + 5*1024);
    bn_finalize_kernel<<<1, 256, 0, stream>>>(stats + 5*1024, s2g2, s2b2, ssb + 5*1024, 256, 1.f/131072.f);
    maxk_kernel<256><<<4096, 256, 0, stream>>>(Y2, ssb + 5*1024, f2tmp);
    transpose_out_kernel<<<256, 256, 0, stream>>>(f2tmp, out);
}

// Round 5
// 1299.146 us; speedup vs baseline: 1.1525x; 1.1525x over previous
//
#include <hip/hip_runtime.h>

#define EPSF 1e-5f

using short8  = __attribute__((ext_vector_type(8))) short;
using float4v = __attribute__((ext_vector_type(4))) float;

__device__ __forceinline__ unsigned short f2bf(float f){
    unsigned u = __float_as_uint(f);
    unsigned r = u + 0x7FFFu + ((u >> 16) & 1u);
    return (unsigned short)(r >> 16);
}
__device__ __forceinline__ float bf2f(unsigned short h){
    return __uint_as_float(((unsigned)h) << 16);
}
// monotone map: ascending float (incl. negatives) -> ascending uint
__device__ __forceinline__ unsigned monou(float f){
    unsigned u = __float_as_uint(f);
    return u ^ (((unsigned)((int)u >> 31)) | 0x80000000u);
}

// ---------------- point_cbr stage ----------------

__global__ __launch_bounds__(256) void pc1_kernel(const float* __restrict__ x,
                                                  const float* __restrict__ w1,
                                                  float* __restrict__ y){
    __shared__ float w[192];
    int t = threadIdx.x;
    if (t < 192) w[t] = w1[t];
    __syncthreads();
    int gid = blockIdx.x * 256 + t;       // over B*N
    int b = gid >> 12;
    int n = gid & 4095;
    const float* xb = x + (size_t)b * 3 * 4096;
    float x0 = xb[n], x1 = xb[4096 + n], x2 = xb[8192 + n];
    float* yb = y + (size_t)b * 64 * 4096;
    #pragma unroll
    for (int o = 0; o < 64; o++){
        float v = x0 * w[o*3] + x1 * w[o*3+1] + x2 * w[o*3+2];
        yb[(size_t)o * 4096 + n] = v;
    }
}

template<int C, int NN>
__global__ __launch_bounds__(256) void stats_bcn_kernel(const float* __restrict__ y,
                                                        float* __restrict__ sums){
    int blk = blockIdx.x;                  // b*C + c
    int c = blk % C;
    const float* p = y + (size_t)blk * NN;
    float s = 0.f, q = 0.f;
    for (int i = threadIdx.x; i < NN; i += 256){ float v = p[i]; s += v; q += v*v; }
    for (int o = 32; o > 0; o >>= 1){ s += __shfl_down(s, o, 64); q += __shfl_down(q, o, 64); }
    __shared__ float ls[4], lq[4];
    int w = threadIdx.x >> 6;
    if ((threadIdx.x & 63) == 0){ ls[w] = s; lq[w] = q; }
    __syncthreads();
    if (threadIdx.x == 0){
        s = ls[0] + ls[1] + ls[2] + ls[3];
        q = lq[0] + lq[1] + lq[2] + lq[3];
        atomicAdd(&sums[c], s);
        atomicAdd(&sums[C + c], q);
    }
}

__global__ void bn_finalize_kernel(const float* __restrict__ sums,
                                   const float* __restrict__ g,
                                   const float* __restrict__ bb,
                                   float* __restrict__ ss, int C, float invCnt){
    int c = blockIdx.x * blockDim.x + threadIdx.x;
    if (c < C){
        float m = sums[c] * invCnt;
        float v = sums[C + c] * invCnt - m * m;
        float sc = g[c] / sqrtf(v + EPSF);
        ss[c] = sc;
        ss[C + c] = bb[c] - m * sc;
    }
}

__global__ __launch_bounds__(256) void pc2_kernel(const float* __restrict__ y1,
                                                  const float* __restrict__ w2,
                                                  const float* __restrict__ ss,
                                                  float* __restrict__ y2){
    __shared__ float wt[64*64];   // wt[c*64+o] = w2[o*64+c]
    __shared__ float lss[128];
    int t = threadIdx.x;
    for (int i = t; i < 4096; i += 256){ int o = i & 63, c = i >> 6; wt[c*64+o] = w2[o*64+c]; }
    if (t < 128) lss[t] = ss[t];
    __syncthreads();
    int gid = blockIdx.x * 256 + t;
    int b = gid >> 12, n = gid & 4095;
    const float* yb = y1 + (size_t)b * 64 * 4096;
    float acc[64];
    #pragma unroll
    for (int o = 0; o < 64; o++) acc[o] = 0.f;
    for (int c = 0; c < 64; c++){
        float v = yb[(size_t)c * 4096 + n];
        v = fmaxf(v * lss[c] + lss[64 + c], 0.f);
        #pragma unroll
        for (int o = 0; o < 64; o++) acc[o] += v * wt[c*64 + o];
    }
    float* ob = y2 + (size_t)b * 64 * 4096;
    #pragma unroll
    for (int o = 0; o < 64; o++) ob[(size_t)o * 4096 + n] = acc[o];
}

// y2 (B,64,N) --bn+relu--> f (B,N,64)
__global__ __launch_bounds__(256) void transpose_f_kernel(const float* __restrict__ y2,
                                                          const float* __restrict__ ss,
                                                          float* __restrict__ f){
    __shared__ float tile[64][65];
    __shared__ float lss[128];
    int t = threadIdx.x;
    if (t < 128) lss[t] = ss[t];
    __syncthreads();
    int blk = blockIdx.x;               // b*(N/64) + ntile
    int b = blk >> 6;
    int nb = (blk & 63) * 64;
    const float* yb = y2 + (size_t)b * 64 * 4096;
    #pragma unroll
    for (int r = 0; r < 16; r++){
        int c = r * 4 + (t >> 6);
        int n = t & 63;
        float v = yb[(size_t)c * 4096 + nb + n];
        tile[c][n] = fmaxf(v * lss[c] + lss[64 + c], 0.f);
    }
    __syncthreads();
    float* fb = f + (size_t)b * 4096 * 64;
    #pragma unroll
    for (int r = 0; r < 16; r++){
        int n = r * 4 + (t >> 6);
        int c = t & 63;
        fb[(size_t)(nb + n) * 64 + c] = tile[c][n];
    }
}

// ---------------- FPS ----------------
// R2 structure (404us known-good: in-loop t==0 stores are free — they complete
// during the same iteration's P-loop; lx[cur] LDS centroid reads; key-only
// cross-wave slots). R5 change: lane-major point mapping (n = t*P + i) so the
// wave argmax can be an f32 max butterfly + ballot/ffs tie-break (lowest lane
// = lowest n) instead of a u64 butterfly — halves shuffle traffic in the
// longest-latency segment. Cross-wave slots keep (d_bits<<32)|~n u64 max-scan.
template<int NP, int SO, int TPB, bool STRIDED>
__global__ __launch_bounds__(TPB) void fps_kernel(const float* __restrict__ coords,
                                                  int* __restrict__ fidx,
                                                  float* __restrict__ xyz_out){
    __shared__ float lx[NP], ly[NP], lz[NP];
    constexpr int W = TPB / 64;
    __shared__ unsigned long long red[2][W];
    const int b = blockIdx.x, t = threadIdx.x;
    constexpr int P = NP / TPB;
    const float* cb = coords + (size_t)b * 3 * NP;
    float px[P], py[P], pz[P], dist[P];
    // coalesced staging into LDS
    #pragma unroll
    for (int i = 0; i < P; i++){
        int n = i * TPB + t;
        float X, Y, Z;
        if (STRIDED){ X = cb[n]; Y = cb[NP + n]; Z = cb[2*NP + n]; }
        else        { X = cb[n*3]; Y = cb[n*3+1]; Z = cb[n*3+2]; }
        lx[n] = X; ly[n] = Y; lz[n] = Z;
    }
    __syncthreads();
    // lane-major register copy: this thread owns points [t*P, t*P+P)
    #pragma unroll
    for (int i = 0; i < P; i++){
        int n = t * P + i;
        px[i] = lx[n]; py[i] = ly[n]; pz[i] = lz[n];
        dist[i] = 1e10f;
    }
    int cur = 0;
    for (int it = 0; it < SO; ++it){
        if (t == 0){
            fidx[b * SO + it] = cur;
            float* xo = xyz_out + ((size_t)b * SO + it) * 3;
            xo[0] = lx[cur]; xo[1] = ly[cur]; xo[2] = lz[cur];
        }
        float cx = lx[cur], cy = ly[cur], cz = lz[cur];
        float bd = -1.f;
        int bn = 0;
        {
            #pragma clang fp contract(off)
            #pragma unroll
            for (int i = 0; i < P; i++){
                float dx = px[i] - cx, dy = py[i] - cy, dz = pz[i] - cz;
                float d = (dx*dx + dy*dy) + dz*dz;   // match np: no fma, ((x+y)+z)
                float nd = fminf(dist[i], d);
                dist[i] = nd;
                if (nd > bd){ bd = nd; bn = t * P + i; }  // strict >: lowest i (= lowest n)
            }
        }
        // f32 max butterfly (dist >= 0, no NaN)
        float m = bd;
        #pragma unroll
        for (int o = 32; o > 0; o >>= 1){
            float v = __shfl_xor(m, o, 64);
            m = fmaxf(m, v);
        }
        // lowest lane with bd == m -> lowest n within wave (lane-major)
        unsigned long long msk = __ballot(bd == m);
        int wl = (int)(__ffsll(msk) - 1);
        int n_w = __shfl(bn, wl, 64);
        if constexpr (W == 1){
            cur = n_w;
        } else {
            int par = it & 1;
            if ((t & 63) == 0){
                red[par][t >> 6] = ((unsigned long long)__float_as_uint(m) << 32)
                                 | (unsigned)(0xFFFFFFFFu - (unsigned)n_w);
            }
            __syncthreads();
            unsigned long long best = red[par][0];
            #pragma unroll
            for (int j = 1; j < W; j++){
                unsigned long long v = red[par][j];
                best = best > v ? best : v;
            }
            cur = (int)(0xFFFFFFFFu - (unsigned)(best & 0xFFFFFFFFull));
        }
    }
}

// ---------------- kNN (exact top-32 by (dist, idx)) ----------------

template<int NC, int SO, bool STRIDED>
__global__ __launch_bounds__(64) void knn_kernel(const float* __restrict__ coords,
                                                 const float* __restrict__ samp,
                                                 int* __restrict__ knno){
    const int blk = blockIdx.x;
    const int b = blk / SO, s = blk % SO;
    const int lane = threadIdx.x;
    const float* cb = coords + (size_t)b * 3 * NC;
    const float* a = samp + ((size_t)b * SO + s) * 3;
    float ax = a[0], ay = a[1], az = a[2];
    float asq = ax*ax + ay*ay + az*az;
    constexpr int J = NC / 64;
    unsigned long long t8[8];
    #pragma unroll
    for (int i = 0; i < 8; i++) t8[i] = ~0ULL;
    for (int j = 0; j < J; j++){
        int n = j * 64 + lane;
        float bx, by, bz;
        if (STRIDED){ bx = cb[n]; by = cb[NC + n]; bz = cb[2*NC + n]; }
        else        { bx = cb[n*3]; by = cb[n*3+1]; bz = cb[n*3+2]; }
        float bsq = bx*bx + by*by + bz*bz;
        float dot = ax*bx + ay*by + az*bz;
        float d = (asq + bsq) - 2.0f * dot;       // reference's formula
        unsigned long long key = ((unsigned long long)monou(d) << 32) | (unsigned)n;
        if (key < t8[7]){
            t8[7] = key;
            #pragma unroll
            for (int i = 6; i >= 0; i--){
                if (t8[i] > t8[i+1]){ unsigned long long tm = t8[i]; t8[i] = t8[i+1]; t8[i+1] = tm; }
            }
        }
    }
    unsigned long long cur = t8[0];
    int myout = 0;
    bool bad = false;
    int popped = 0;
    for (int r = 0; r < 32; r++){
        unsigned long long m = cur;
        #pragma unroll
        for (int o2 = 32; o2 > 0; o2 >>= 1){
            unsigned long long v = __shfl_xor(m, o2, 64);
            m = m < v ? m : v;
        }
        if (lane == r) myout = (int)(unsigned)(m & 0xFFFFFFFFull);
        if (cur == m){
            #pragma unroll
            for (int i = 0; i < 7; i++) t8[i] = t8[i+1];
            t8[7] = ~0ULL;
            cur = t8[0];
            popped++;
            if (J > 8 && popped == 8 && r < 31) bad = true;
        }
    }
    if (__any(bad)){
        // exact fallback: ascending total-order scan (keys are unique)
        unsigned long long last = 0;
        for (int r = 0; r < 32; r++){
            unsigned long long mk = ~0ULL;
            for (int j = 0; j < J; j++){
                int n = j * 64 + lane;
                float bx, by, bz;
                if (STRIDED){ bx = cb[n]; by = cb[NC + n]; bz = cb[2*NC + n]; }
                else        { bx = cb[n*3]; by = cb[n*3+1]; bz = cb[n*3+2]; }
                float bsq = bx*bx + by*by + bz*bz;
                float dot = ax*bx + ay*by + az*bz;
                float d = (asq + bsq) - 2.0f * dot;
                unsigned long long key = ((unsigned long long)monou(d) << 32) | (unsigned)n;
                if (key > last && key < mk) mk = key;
            }
            unsigned long long m = mk;
            #pragma unroll
            for (int o2 = 32; o2 > 0; o2 >>= 1){
                unsigned long long v = __shfl_xor(m, o2, 64);
                m = m < v ? m : v;
            }
            if (lane == r) myout = (int)(unsigned)(m & 0xFFFFFFFFull);
            last = m;
        }
    }
    if (lane < 32) knno[((size_t)b * SO + s) * 32 + lane] = myout;
}

// ---------------- MFMA grouped MLP ----------------

template<int O, int D>
__global__ __launch_bounds__(256) void pack_w_kernel(const float* __restrict__ w,
                                                     unsigned short* __restrict__ pk){
    int tid = blockIdx.x * 256 + threadIdx.x;
    constexpr int CH = D / 32;
    constexpr int TOT = (O/16) * CH * 64;
    if (tid >= TOT) return;
    int lane = tid & 63;
    int fc = tid >> 6;
    int ch = fc % CH;
    int ot = fc / CH;
    int o  = ot * 16 + (lane & 15);
    int kb = ch * 32 + (lane >> 4) * 8;
    #pragma unroll
    for (int j = 0; j < 8; j++) pk[(size_t)tid * 8 + j] = f2bf(w[(size_t)o * D + kb + j]);
}

template<int D, int O>
__device__ __forceinline__ void mfma_compute_store(const short* A, const short* wp,
                                                   unsigned short* Y, float* lsum, float* lsq,
                                                   int blk, int t){
    constexpr int RS = D + 8;
    constexpr int CH = D / 32;
    constexpr int OT = O / 16;
    constexpr int OPW = OT / 4;
    int lane = t & 63, wv = t >> 6;
    int col = lane & 15, quad = lane >> 4;
    for (int oi = 0; oi < OPW; ++oi){
        int ot = wv * OPW + oi;
        for (int mt = 0; mt < 4; ++mt){
            float4v acc = {0.f, 0.f, 0.f, 0.f};
            #pragma unroll
            for (int ch = 0; ch < CH; ++ch){
                short8 a  = *(const short8*)(A + (mt*16 + col) * RS + ch*32 + quad*8);
                short8 bf = *(const short8*)(wp + ((size_t)(ot*CH + ch) * 64 + lane) * 8);
                acc = __builtin_amdgcn_mfma_f32_16x16x32_bf16(a, bf, acc, 0, 0, 0);
            }
            float s4 = 0.f, q4 = 0.f;
            size_t rowbase = (size_t)blk * 64 + mt * 16 + quad * 4;
            #pragma unroll
            for (int r = 0; r < 4; r++){
                float v = acc[r];
                s4 += v; q4 += v * v;
                Y[(rowbase + r) * O + ot * 16 + col] = f2bf(v);
            }
            s4 += __shfl_xor(s4, 16, 64); s4 += __shfl_xor(s4, 32, 64);
            q4 += __shfl_xor(q4, 16, 64); q4 += __shfl_xor(q4, 32, 64);
            if (quad == 0){ lsum[ot*16 + col] += s4; lsq[ot*16 + col] += q4; }
        }
    }
}

// layer1: gather + [f_nb - f_c | f_c] -> bf16 LDS -> MFMA, store Y bf16 + stats
template<int DH, int O, int S, int NPTS>
__global__ __launch_bounds__(256) void gemm1_kernel(const float* __restrict__ fsrc,
                                                    const int* __restrict__ fidx,
                                                    const int* __restrict__ knn,
                                                    const short* __restrict__ wp,
                                                    unsigned short* __restrict__ Y,
                                                    float* __restrict__ sums){
    constexpr int D = 2 * DH;
    constexpr int RS = D + 8;
    __shared__ __align__(16) short A[64 * RS];
    __shared__ float lsum[O], lsq[O];
    int t = threadIdx.x;
    for (int i = t; i < O; i += 256){ lsum[i] = 0.f; lsq[i] = 0.f; }
    int blk = blockIdx.x;
    for (int g = 0; g < 2; ++g){
        int gid = blk * 2 + g;
        int b = gid / S;
        int cidx = fidx[gid];
        const float* fc = fsrc + ((size_t)b * NPTS + cidx) * DH;
        int kk = t >> 3;
        int p  = t & 7;
        int nb = knn[(size_t)gid * 32 + kk];
        const float* fn = fsrc + ((size_t)b * NPTS + nb) * DH;
        constexpr int E = D / 8;
        int d0 = p * E;
        short* row = A + (g * 32 + kk) * RS;
        #pragma unroll
        for (int e = 0; e < E; e++){
            int d = d0 + e;
            float v = (d < DH) ? (fn[d] - fc[d]) : fc[d - DH];
            row[d] = (short)f2bf(v);
        }
    }
    __syncthreads();
    mfma_compute_store<D, O>(A, wp, Y, lsum, lsq, blk, t);
    __syncthreads();
    for (int i = t; i < O; i += 256){
        atomicAdd(&sums[i], lsum[i]);
        atomicAdd(&sums[O + i], lsq[i]);
    }
}

// layer2: bn+relu(Yin) -> bf16 LDS -> MFMA, store Y bf16 + stats
template<int D, int O>
__global__ __launch_bounds__(256) void gemm2_kernel(const unsigned short* __restrict__ Yin,
                                                    const float* __restrict__ ss,
                                                    const short* __restrict__ wp,
                                                    unsigned short* __restrict__ Y,
                                                    float* __restrict__ sums){
    constexpr int RS = D + 8;
    __shared__ __align__(16) short A[64 * RS];
    __shared__ float lsum[O], lsq[O];
    __shared__ float lss[2 * D];
    int t = threadIdx.x;
    for (int i = t; i < O; i += 256){ lsum[i] = 0.f; lsq[i] = 0.f; }
    for (int i = t; i < 2*D; i += 256) lss[i] = ss[i];
    __syncthreads();
    int blk = blockIdx.x;
    {
        int row = t >> 2;
        int d0 = (t & 3) * (D / 4);
        const unsigned short* src = Yin + ((size_t)blk * 64 + row) * D + d0;
        short* dst = A + row * RS + d0;
        #pragma unroll
        for (int e = 0; e < D/4; e++){
            float v = bf2f(src[e]);
            int d = d0 + e;
            v = fmaxf(v * lss[d] + lss[D + d], 0.f);
            dst[e] = (short)f2bf(v);
        }
    }
    __syncthreads();
    mfma_compute_store<D, O>(A, wp, Y, lsum, lsq, blk, t);
    __syncthreads();
    for (int i = t; i < O; i += 256){
        atomicAdd(&sums[i], lsum[i]);
        atomicAdd(&sums[O + i], lsq[i]);
    }
}

template<int O>
__global__ __launch_bounds__(256) void maxk_kernel(const unsigned short* __restrict__ Y,
                                                   const float* __restrict__ ss,
                                                   float* __restrict__ out){
    int gid = blockIdx.x * 256 + threadIdx.x;
    int o = gid % O;
    int r = gid / O;
    float sc = ss[o], sh = ss[O + o];
    const unsigned short* p = Y + (size_t)r * 32 * O + o;
    float m = -1e30f;
    #pragma unroll 8
    for (int k = 0; k < 32; k++){
        float v = bf2f(p[(size_t)k * O]);
        m = fmaxf(m, v * sc + sh);
    }
    out[gid] = fmaxf(m, 0.f);
}

// (B,256s,256o) -> (B,256o,256s)
__global__ __launch_bounds__(256) void transpose_out_kernel(const float* __restrict__ in,
                                                            float* __restrict__ out){
    __shared__ float tile[64][65];
    int blk = blockIdx.x;
    int b = blk >> 4;
    int ot = (blk >> 2) & 3, st = blk & 3;
    int t = threadIdx.x;
    const float* ib = in + (size_t)b * 65536;
    float* ob = out + (size_t)b * 65536;
    #pragma unroll
    for (int r = 0; r < 16; r++){
        int srow = st * 64 + r * 4 + (t >> 6);
        int o = ot * 64 + (t & 63);
        tile[r * 4 + (t >> 6)][t & 63] = ib[srow * 256 + o];
    }
    __syncthreads();
    #pragma unroll
    for (int r = 0; r < 16; r++){
        int o = ot * 64 + r * 4 + (t >> 6);
        int srow = st * 64 + (t & 63);
        ob[o * 256 + srow] = tile[t & 63][r * 4 + (t >> 6)];
    }
}

extern "C" void kernel_launch(void* const* d_in, const int* in_sizes, int n_in,
                              void* d_out, int out_size, void* d_ws, size_t ws_size,
                              hipStream_t stream) {
    const float* x    = (const float*)d_in[0];
    const float* w1   = (const float*)d_in[1];
    const float* w2   = (const float*)d_in[2];
    const float* g1   = (const float*)d_in[3];
    const float* b1   = (const float*)d_in[4];
    const float* g2   = (const float*)d_in[5];
    const float* b2   = (const float*)d_in[6];
    const float* s1w1 = (const float*)d_in[7];
    const float* s1w2 = (const float*)d_in[8];
    const float* s1g1 = (const float*)d_in[9];
    const float* s1b1 = (const float*)d_in[10];
    const float* s1g2 = (const float*)d_in[11];
    const float* s1b2 = (const float*)d_in[12];
    const float* s2w1 = (const float*)d_in[13];
    const float* s2w2 = (const float*)d_in[14];
    const float* s2g1 = (const float*)d_in[15];
    const float* s2b1 = (const float*)d_in[16];
    const float* s2g2 = (const float*)d_in[17];
    const float* s2b2 = (const float*)d_in[18];
    float* out = (float*)d_out;

    char* ws = (char*)d_ws;
    size_t off = 0;
    auto take = [&](size_t bytes){ size_t r = off; off += (bytes + 255) & ~(size_t)255; return r; };
    float* f_buf   = (float*)(ws + take(16u*4096u*64u*4u));      // f (B,N,64)
    float* f1_buf  = (float*)(ws + take(16u*512u*128u*4u));      // f1 (B,S1,128)
    int*   fidx1   = (int*)  (ws + take(16u*512u*4u));
    float* xyz1    = (float*)(ws + take(16u*512u*3u*4u));
    int*   fidx2   = (int*)  (ws + take(16u*256u*4u));
    float* xyz2    = (float*)(ws + take(16u*256u*3u*4u));
    int*   knn1    = (int*)  (ws + take(16u*512u*32u*4u));
    int*   knn2    = (int*)  (ws + take(16u*256u*32u*4u));
    unsigned short* wp1 = (unsigned short*)(ws + take(128u*128u*2u));
    unsigned short* wp2 = (unsigned short*)(ws + take(128u*128u*2u));
    unsigned short* wp3 = (unsigned short*)(ws + take(256u*256u*2u));
    unsigned short* wp4 = (unsigned short*)(ws + take(256u*256u*2u));
    float* stats   = (float*)(ws + take(6u*1024u*4u));
    float* ssb     = (float*)(ws + take(6u*1024u*4u));
    float* f2tmp   = (float*)(ws + take(16u*256u*256u*4u));
    char*  regA    = ws + take(67108864u);
    char*  regB    = ws + take(67108864u);
    (void)in_sizes; (void)n_in; (void)out_size; (void)ws_size;

    hipMemsetAsync(stats, 0, 6u*1024u*4u, stream);

    pack_w_kernel<128,128><<<8, 256, 0, stream>>>(s1w1, wp1);
    pack_w_kernel<128,128><<<8, 256, 0, stream>>>(s1w2, wp2);
    pack_w_kernel<256,256><<<32, 256, 0, stream>>>(s2w1, wp3);
    pack_w_kernel<256,256><<<32, 256, 0, stream>>>(s2w2, wp4);

    float* yA = (float*)regA;
    float* yB = (float*)regB;
    pc1_kernel<<<256, 256, 0, stream>>>(x, w1, yA);
    stats_bcn_kernel<64,4096><<<1024, 256, 0, stream>>>(yA, stats + 0*1024);
    bn_finalize_kernel<<<1, 256, 0, stream>>>(stats + 0*1024, g1, b1, ssb + 0*1024, 64, 1.f/65536.f);
    pc2_kernel<<<256, 256, 0, stream>>>(yA, w2, ssb + 0*1024, yB);
    stats_bcn_kernel<64,4096><<<1024, 256, 0, stream>>>(yB, stats + 1*1024);
    bn_finalize_kernel<<<1, 256, 0, stream>>>(stats + 1*1024, g2, b2, ssb + 1*1024, 64, 1.f/65536.f);
    transpose_f_kernel<<<1024, 256, 0, stream>>>(yB, ssb + 1*1024, f_buf);

    fps_kernel<4096,512,256,true><<<16, 256, 0, stream>>>(x, fidx1, xyz1);
    knn_kernel<4096,512,true><<<8192, 64, 0, stream>>>(x, xyz1, knn1);

    unsigned short* Y1 = (unsigned short*)regA;
    unsigned short* Y2 = (unsigned short*)regB;
    gemm1_kernel<64,128,512,4096><<<4096, 256, 0, stream>>>(f_buf, fidx1, knn1, (const short*)wp1, Y1, stats + 2*1024);
    bn_finalize_kernel<<<1, 256, 0, stream>>>(stats + 2*1024, s1g1, s1b1, ssb + 2*1024, 128, 1.f/262144.f);
    gemm2_kernel<128,128><<<4096, 256, 0, stream>>>(Y1, ssb + 2*1024, (const short*)wp2, Y2, stats + 3*1024);
    bn_finalize_kernel<<<1, 256, 0, stream>>>(stats + 3*1024, s1g2, s1b2, ssb + 3*1024, 128, 1.f/262144.f);
    maxk_kernel<128><<<4096, 256, 0, stream>>>(Y2, ssb + 3*1024, f1_buf);

    fps_kernel<512,256,64,false><<<16, 64, 0, stream>>>(xyz1, fidx2, xyz2);
    knn_kernel<512,256,false><<<4096, 64, 0, stream>>>(xyz1, xyz2, knn2);

    gemm1_kernel<128,256,256,512><<<2048, 256, 0, stream>>>(f1_buf, fidx2, knn2, (const short*)wp3, Y1, stats + 4*1024);
    bn_finalize_kernel<<<1, 256, 0, stream>>>(stats + 4*1024, s2g1, s2b1, ssb + 4*1024, 256, 1.f/131072.f);
    gemm2_kernel<256,256><<<2048, 256, 0, stream>>>(Y1, ssb + 4*1024, (const short*)wp4, Y2, stats + 5*1024);
    bn_finalize_kernel<<<1, 256, 0, stream>>>(stats + 5*1024, s2g2, s2b2, ssb + 5*1024, 256, 1.f/131072.f);
    maxk_kernel<256><<<4096, 256, 0, stream>>>(Y2, ssb + 5*1024, f2tmp);
    transpose_out_kernel<<<256, 256, 0, stream>>>(f2tmp, out);
}

// Round 6
// 1190.812 us; speedup vs baseline: 1.2573x; 1.0910x over previous
//
#include <hip/hip_runtime.h>

#define EPSF 1e-5f

using short8  = __attribute__((ext_vector_type(8))) short;
using float4v = __attribute__((ext_vector_type(4))) float;

__device__ __forceinline__ unsigned short f2bf(float f){
    unsigned u = __float_as_uint(f);
    unsigned r = u + 0x7FFFu + ((u >> 16) & 1u);
    return (unsigned short)(r >> 16);
}
__device__ __forceinline__ float bf2f(unsigned short h){
    return __uint_as_float(((unsigned)h) << 16);
}
// monotone map: ascending float (incl. negatives) -> ascending uint
__device__ __forceinline__ unsigned monou(float f){
    unsigned u = __float_as_uint(f);
    return u ^ (((unsigned)((int)u >> 31)) | 0x80000000u);
}

// DPP-based wave64 f32 max stage: VALU latency (~8cyc) instead of ds_bpermute
// (~120cyc). old=src => masked/invalid lanes keep own value (identity for max).
template<int CTRL, int RMASK>
__device__ __forceinline__ float fmax_dpp(float x){
    int xi = __float_as_int(x);
    int yi = __builtin_amdgcn_update_dpp(xi, xi, CTRL, RMASK, 0xf, false);
    return fmaxf(x, __int_as_float(yi));
}
// full wave64 max (values >= 0, no NaN); result valid in lane 63, broadcast via readlane
__device__ __forceinline__ float wave_max_dpp(float x){
    x = fmax_dpp<0x111, 0xf>(x);  // row_shr:1
    x = fmax_dpp<0x112, 0xf>(x);  // row_shr:2
    x = fmax_dpp<0x114, 0xf>(x);  // row_shr:4
    x = fmax_dpp<0x118, 0xf>(x);  // row_shr:8  -> lane15/31/47/63 hold row maxes
    x = fmax_dpp<0x142, 0xa>(x);  // row_bcast15 -> lanes 31,63 hold half maxes
    x = fmax_dpp<0x143, 0xc>(x);  // row_bcast31 -> lane 63 holds wave max
    return __int_as_float(__builtin_amdgcn_readlane(__float_as_int(x), 63));
}

// ---------------- point_cbr stage ----------------

__global__ __launch_bounds__(256) void pc1_kernel(const float* __restrict__ x,
                                                  const float* __restrict__ w1,
                                                  float* __restrict__ y){
    __shared__ float w[192];
    int t = threadIdx.x;
    if (t < 192) w[t] = w1[t];
    __syncthreads();
    int gid = blockIdx.x * 256 + t;       // over B*N
    int b = gid >> 12;
    int n = gid & 4095;
    const float* xb = x + (size_t)b * 3 * 4096;
    float x0 = xb[n], x1 = xb[4096 + n], x2 = xb[8192 + n];
    float* yb = y + (size_t)b * 64 * 4096;
    #pragma unroll
    for (int o = 0; o < 64; o++){
        float v = x0 * w[o*3] + x1 * w[o*3+1] + x2 * w[o*3+2];
        yb[(size_t)o * 4096 + n] = v;
    }
}

template<int C, int NN>
__global__ __launch_bounds__(256) void stats_bcn_kernel(const float* __restrict__ y,
                                                        float* __restrict__ sums){
    int blk = blockIdx.x;                  // b*C + c
    int c = blk % C;
    const float* p = y + (size_t)blk * NN;
    float s = 0.f, q = 0.f;
    for (int i = threadIdx.x; i < NN; i += 256){ float v = p[i]; s += v; q += v*v; }
    for (int o = 32; o > 0; o >>= 1){ s += __shfl_down(s, o, 64); q += __shfl_down(q, o, 64); }
    __shared__ float ls[4], lq[4];
    int w = threadIdx.x >> 6;
    if ((threadIdx.x & 63) == 0){ ls[w] = s; lq[w] = q; }
    __syncthreads();
    if (threadIdx.x == 0){
        s = ls[0] + ls[1] + ls[2] + ls[3];
        q = lq[0] + lq[1] + lq[2] + lq[3];
        atomicAdd(&sums[c], s);
        atomicAdd(&sums[C + c], q);
    }
}

__global__ void bn_finalize_kernel(const float* __restrict__ sums,
                                   const float* __restrict__ g,
                                   const float* __restrict__ bb,
                                   float* __restrict__ ss, int C, float invCnt){
    int c = blockIdx.x * blockDim.x + threadIdx.x;
    if (c < C){
        float m = sums[c] * invCnt;
        float v = sums[C + c] * invCnt - m * m;
        float sc = g[c] / sqrtf(v + EPSF);
        ss[c] = sc;
        ss[C + c] = bb[c] - m * sc;
    }
}

__global__ __launch_bounds__(256) void pc2_kernel(const float* __restrict__ y1,
                                                  const float* __restrict__ w2,
                                                  const float* __restrict__ ss,
                                                  float* __restrict__ y2){
    __shared__ float wt[64*64];   // wt[c*64+o] = w2[o*64+c]
    __shared__ float lss[128];
    int t = threadIdx.x;
    for (int i = t; i < 4096; i += 256){ int o = i & 63, c = i >> 6; wt[c*64+o] = w2[o*64+c]; }
    if (t < 128) lss[t] = ss[t];
    __syncthreads();
    int gid = blockIdx.x * 256 + t;
    int b = gid >> 12, n = gid & 4095;
    const float* yb = y1 + (size_t)b * 64 * 4096;
    float acc[64];
    #pragma unroll
    for (int o = 0; o < 64; o++) acc[o] = 0.f;
    for (int c = 0; c < 64; c++){
        float v = yb[(size_t)c * 4096 + n];
        v = fmaxf(v * lss[c] + lss[64 + c], 0.f);
        #pragma unroll
        for (int o = 0; o < 64; o++) acc[o] += v * wt[c*64 + o];
    }
    float* ob = y2 + (size_t)b * 64 * 4096;
    #pragma unroll
    for (int o = 0; o < 64; o++) ob[(size_t)o * 4096 + n] = acc[o];
}

// y2 (B,64,N) --bn+relu--> f (B,N,64)
__global__ __launch_bounds__(256) void transpose_f_kernel(const float* __restrict__ y2,
                                                          const float* __restrict__ ss,
                                                          float* __restrict__ f){
    __shared__ float tile[64][65];
    __shared__ float lss[128];
    int t = threadIdx.x;
    if (t < 128) lss[t] = ss[t];
    __syncthreads();
    int blk = blockIdx.x;               // b*(N/64) + ntile
    int b = blk >> 6;
    int nb = (blk & 63) * 64;
    const float* yb = y2 + (size_t)b * 64 * 4096;
    #pragma unroll
    for (int r = 0; r < 16; r++){
        int c = r * 4 + (t >> 6);
        int n = t & 63;
        float v = yb[(size_t)c * 4096 + nb + n];
        tile[c][n] = fmaxf(v * lss[c] + lss[64 + c], 0.f);
    }
    __syncthreads();
    float* fb = f + (size_t)b * 4096 * 64;
    #pragma unroll
    for (int r = 0; r < 16; r++){
        int n = r * 4 + (t >> 6);
        int c = t & 63;
        fb[(size_t)(nb + n) * 64 + c] = tile[c][n];
    }
}

// ---------------- FPS ----------------
// R2 structure (in-loop t==0 stores are free; lx[cur] LDS centroid reads;
// key-only cross-wave slots). R6 change: wave argmax via DPP max-reduction
// (6 VALU-latency stages, ~60cyc) + ballot/ffs/readlane tie-break, replacing
// the 6-stage ds_bpermute butterfly (~720cyc latency chain). Lane-major point
// mapping (n = t*P + i) keeps lowest-lane = lowest-n exact tie-break.
template<int NP, int SO, int TPB, bool STRIDED>
__global__ __launch_bounds__(TPB) void fps_kernel(const float* __restrict__ coords,
                                                  int* __restrict__ fidx,
                                                  float* __restrict__ xyz_out){
    __shared__ float lx[NP], ly[NP], lz[NP];
    constexpr int W = TPB / 64;
    __shared__ unsigned long long red[2][W];
    const int b = blockIdx.x, t = threadIdx.x;
    constexpr int P = NP / TPB;
    const float* cb = coords + (size_t)b * 3 * NP;
    float px[P], py[P], pz[P], dist[P];
    // coalesced staging into LDS
    #pragma unroll
    for (int i = 0; i < P; i++){
        int n = i * TPB + t;
        float X, Y, Z;
        if (STRIDED){ X = cb[n]; Y = cb[NP + n]; Z = cb[2*NP + n]; }
        else        { X = cb[n*3]; Y = cb[n*3+1]; Z = cb[n*3+2]; }
        lx[n] = X; ly[n] = Y; lz[n] = Z;
    }
    __syncthreads();
    // lane-major register copy: this thread owns points [t*P, t*P+P)
    #pragma unroll
    for (int i = 0; i < P; i++){
        int n = t * P + i;
        px[i] = lx[n]; py[i] = ly[n]; pz[i] = lz[n];
        dist[i] = 1e10f;
    }
    int cur = 0;
    for (int it = 0; it < SO; ++it){
        if (t == 0){
            fidx[b * SO + it] = cur;
            float* xo = xyz_out + ((size_t)b * SO + it) * 3;
            xo[0] = lx[cur]; xo[1] = ly[cur]; xo[2] = lz[cur];
        }
        float cx = lx[cur], cy = ly[cur], cz = lz[cur];
        float bd = -1.f;
        int bn = 0;
        {
            #pragma clang fp contract(off)
            #pragma unroll
            for (int i = 0; i < P; i++){
                float dx = px[i] - cx, dy = py[i] - cy, dz = pz[i] - cz;
                float d = (dx*dx + dy*dy) + dz*dz;   // match np: no fma, ((x+y)+z)
                float nd = fminf(dist[i], d);
                dist[i] = nd;
                if (nd > bd){ bd = nd; bn = t * P + i; }  // strict >: lowest i (= lowest n)
            }
        }
        // wave max via DPP (bd >= 0 after loop), then exact lowest-n tie-break
        float wm = wave_max_dpp(bd);
        unsigned long long msk = __ballot(bd == wm);
        int wl = (int)(__ffsll(msk) - 1);
        int n_w = __builtin_amdgcn_readlane(bn, wl);
        if constexpr (W == 1){
            cur = n_w;
        } else {
            int par = it & 1;
            if ((t & 63) == 0){
                red[par][t >> 6] = ((unsigned long long)__float_as_uint(wm) << 32)
                                 | (unsigned)(0xFFFFFFFFu - (unsigned)n_w);
            }
            __syncthreads();
            unsigned long long best = red[par][0];
            #pragma unroll
            for (int j = 1; j < W; j++){
                unsigned long long v = red[par][j];
                best = best > v ? best : v;
            }
            cur = (int)(0xFFFFFFFFu - (unsigned)(best & 0xFFFFFFFFull));
        }
    }
}

// ---------------- kNN (exact top-32 by (dist, idx)) ----------------

template<int NC, int SO, bool STRIDED>
__global__ __launch_bounds__(64) void knn_kernel(const float* __restrict__ coords,
                                                 const float* __restrict__ samp,
                                                 int* __restrict__ knno){
    const int blk = blockIdx.x;
    const int b = blk / SO, s = blk % SO;
    const int lane = threadIdx.x;
    const float* cb = coords + (size_t)b * 3 * NC;
    const float* a = samp + ((size_t)b * SO + s) * 3;
    float ax = a[0], ay = a[1], az = a[2];
    float asq = ax*ax + ay*ay + az*az;
    constexpr int J = NC / 64;
    unsigned long long t8[8];
    #pragma unroll
    for (int i = 0; i < 8; i++) t8[i] = ~0ULL;
    for (int j = 0; j < J; j++){
        int n = j * 64 + lane;
        float bx, by, bz;
        if (STRIDED){ bx = cb[n]; by = cb[NC + n]; bz = cb[2*NC + n]; }
        else        { bx = cb[n*3]; by = cb[n*3+1]; bz = cb[n*3+2]; }
        float bsq = bx*bx + by*by + bz*bz;
        float dot = ax*bx + ay*by + az*bz;
        float d = (asq + bsq) - 2.0f * dot;       // reference's formula
        unsigned long long key = ((unsigned long long)monou(d) << 32) | (unsigned)n;
        if (key < t8[7]){
            t8[7] = key;
            #pragma unroll
            for (int i = 6; i >= 0; i--){
                if (t8[i] > t8[i+1]){ unsigned long long tm = t8[i]; t8[i] = t8[i+1]; t8[i+1] = tm; }
            }
        }
    }
    unsigned long long cur = t8[0];
    int myout = 0;
    bool bad = false;
    int popped = 0;
    for (int r = 0; r < 32; r++){
        unsigned long long m = cur;
        #pragma unroll
        for (int o2 = 32; o2 > 0; o2 >>= 1){
            unsigned long long v = __shfl_xor(m, o2, 64);
            m = m < v ? m : v;
        }
        if (lane == r) myout = (int)(unsigned)(m & 0xFFFFFFFFull);
        if (cur == m){
            #pragma unroll
            for (int i = 0; i < 7; i++) t8[i] = t8[i+1];
            t8[7] = ~0ULL;
            cur = t8[0];
            popped++;
            if (J > 8 && popped == 8 && r < 31) bad = true;
        }
    }
    if (__any(bad)){
        // exact fallback: ascending total-order scan (keys are unique)
        unsigned long long last = 0;
        for (int r = 0; r < 32; r++){
            unsigned long long mk = ~0ULL;
            for (int j = 0; j < J; j++){
                int n = j * 64 + lane;
                float bx, by, bz;
                if (STRIDED){ bx = cb[n]; by = cb[NC + n]; bz = cb[2*NC + n]; }
                else        { bx = cb[n*3]; by = cb[n*3+1]; bz = cb[n*3+2]; }
                float bsq = bx*bx + by*by + bz*bz;
                float dot = ax*bx + ay*by + az*bz;
                float d = (asq + bsq) - 2.0f * dot;
                unsigned long long key = ((unsigned long long)monou(d) << 32) | (unsigned)n;
                if (key > last && key < mk) mk = key;
            }
            unsigned long long m = mk;
            #pragma unroll
            for (int o2 = 32; o2 > 0; o2 >>= 1){
                unsigned long long v = __shfl_xor(m, o2, 64);
                m = m < v ? m : v;
            }
            if (lane == r) myout = (int)(unsigned)(m & 0xFFFFFFFFull);
            last = m;
        }
    }
    if (lane < 32) knno[((size_t)b * SO + s) * 32 + lane] = myout;
}

// ---------------- MFMA grouped MLP ----------------

template<int O, int D>
__global__ __launch_bounds__(256) void pack_w_kernel(const float* __restrict__ w,
                                                     unsigned short* __restrict__ pk){
    int tid = blockIdx.x * 256 + threadIdx.x;
    constexpr int CH = D / 32;
    constexpr int TOT = (O/16) * CH * 64;
    if (tid >= TOT) return;
    int lane = tid & 63;
    int fc = tid >> 6;
    int ch = fc % CH;
    int ot = fc / CH;
    int o  = ot * 16 + (lane & 15);
    int kb = ch * 32 + (lane >> 4) * 8;
    #pragma unroll
    for (int j = 0; j < 8; j++) pk[(size_t)tid * 8 + j] = f2bf(w[(size_t)o * D + kb + j]);
}

template<int D, int O>
__device__ __forceinline__ void mfma_compute_store(const short* A, const short* wp,
                                                   unsigned short* Y, float* lsum, float* lsq,
                                                   int blk, int t){
    constexpr int RS = D + 8;
    constexpr int CH = D / 32;
    constexpr int OT = O / 16;
    constexpr int OPW = OT / 4;
    int lane = t & 63, wv = t >> 6;
    int col = lane & 15, quad = lane >> 4;
    for (int oi = 0; oi < OPW; ++oi){
        int ot = wv * OPW + oi;
        for (int mt = 0; mt < 4; ++mt){
            float4v acc = {0.f, 0.f, 0.f, 0.f};
            #pragma unroll
            for (int ch = 0; ch < CH; ++ch){
                short8 a  = *(const short8*)(A + (mt*16 + col) * RS + ch*32 + quad*8);
                short8 bf = *(const short8*)(wp + ((size_t)(ot*CH + ch) * 64 + lane) * 8);
                acc = __builtin_amdgcn_mfma_f32_16x16x32_bf16(a, bf, acc, 0, 0, 0);
            }
            float s4 = 0.f, q4 = 0.f;
            size_t rowbase = (size_t)blk * 64 + mt * 16 + quad * 4;
            #pragma unroll
            for (int r = 0; r < 4; r++){
                float v = acc[r];
                s4 += v; q4 += v * v;
                Y[(rowbase + r) * O + ot * 16 + col] = f2bf(v);
            }
            s4 += __shfl_xor(s4, 16, 64); s4 += __shfl_xor(s4, 32, 64);
            q4 += __shfl_xor(q4, 16, 64); q4 += __shfl_xor(q4, 32, 64);
            if (quad == 0){ lsum[ot*16 + col] += s4; lsq[ot*16 + col] += q4; }
        }
    }
}

// layer1: gather + [f_nb - f_c | f_c] -> bf16 LDS -> MFMA, store Y bf16 + stats
template<int DH, int O, int S, int NPTS>
__global__ __launch_bounds__(256) void gemm1_kernel(const float* __restrict__ fsrc,
                                                    const int* __restrict__ fidx,
                                                    const int* __restrict__ knn,
                                                    const short* __restrict__ wp,
                                                    unsigned short* __restrict__ Y,
                                                    float* __restrict__ sums){
    constexpr int D = 2 * DH;
    constexpr int RS = D + 8;
    __shared__ __align__(16) short A[64 * RS];
    __shared__ float lsum[O], lsq[O];
    int t = threadIdx.x;
    for (int i = t; i < O; i += 256){ lsum[i] = 0.f; lsq[i] = 0.f; }
    int blk = blockIdx.x;
    for (int g = 0; g < 2; ++g){
        int gid = blk * 2 + g;
        int b = gid / S;
        int cidx = fidx[gid];
        const float* fc = fsrc + ((size_t)b * NPTS + cidx) * DH;
        int kk = t >> 3;
        int p  = t & 7;
        int nb = knn[(size_t)gid * 32 + kk];
        const float* fn = fsrc + ((size_t)b * NPTS + nb) * DH;
        constexpr int E = D / 8;
        int d0 = p * E;
        short* row = A + (g * 32 + kk) * RS;
        #pragma unroll
        for (int e = 0; e < E; e++){
            int d = d0 + e;
            float v = (d < DH) ? (fn[d] - fc[d]) : fc[d - DH];
            row[d] = (short)f2bf(v);
        }
    }
    __syncthreads();
    mfma_compute_store<D, O>(A, wp, Y, lsum, lsq, blk, t);
    __syncthreads();
    for (int i = t; i < O; i += 256){
        atomicAdd(&sums[i], lsum[i]);
        atomicAdd(&sums[O + i], lsq[i]);
    }
}

// layer2: bn+relu(Yin) -> bf16 LDS -> MFMA, store Y bf16 + stats
template<int D, int O>
__global__ __launch_bounds__(256) void gemm2_kernel(const unsigned short* __restrict__ Yin,
                                                    const float* __restrict__ ss,
                                                    const short* __restrict__ wp,
                                                    unsigned short* __restrict__ Y,
                                                    float* __restrict__ sums){
    constexpr int RS = D + 8;
    __shared__ __align__(16) short A[64 * RS];
    __shared__ float lsum[O], lsq[O];
    __shared__ float lss[2 * D];
    int t = threadIdx.x;
    for (int i = t; i < O; i += 256){ lsum[i] = 0.f; lsq[i] = 0.f; }
    for (int i = t; i < 2*D; i += 256) lss[i] = ss[i];
    __syncthreads();
    int blk = blockIdx.x;
    {
        int row = t >> 2;
        int d0 = (t & 3) * (D / 4);
        const unsigned short* src = Yin + ((size_t)blk * 64 + row) * D + d0;
        short* dst = A + row * RS + d0;
        #pragma unroll
        for (int e = 0; e < D/4; e++){
            float v = bf2f(src[e]);
            int d = d0 + e;
            v = fmaxf(v * lss[d] + lss[D + d], 0.f);
            dst[e] = (short)f2bf(v);
        }
    }
    __syncthreads();
    mfma_compute_store<D, O>(A, wp, Y, lsum, lsq, blk, t);
    __syncthreads();
    for (int i = t; i < O; i += 256){
        atomicAdd(&sums[i], lsum[i]);
        atomicAdd(&sums[O + i], lsq[i]);
    }
}

template<int O>
__global__ __launch_bounds__(256) void maxk_kernel(const unsigned short* __restrict__ Y,
                                                   const float* __restrict__ ss,
                                                   float* __restrict__ out){
    int gid = blockIdx.x * 256 + threadIdx.x;
    int o = gid % O;
    int r = gid / O;
    float sc = ss[o], sh = ss[O + o];
    const unsigned short* p = Y + (size_t)r * 32 * O + o;
    float m = -1e30f;
    #pragma unroll 8
    for (int k = 0; k < 32; k++){
        float v = bf2f(p[(size_t)k * O]);
        m = fmaxf(m, v * sc + sh);
    }
    out[gid] = fmaxf(m, 0.f);
}

// (B,256s,256o) -> (B,256o,256s)
__global__ __launch_bounds__(256) void transpose_out_kernel(const float* __restrict__ in,
                                                            float* __restrict__ out){
    __shared__ float tile[64][65];
    int blk = blockIdx.x;
    int b = blk >> 4;
    int ot = (blk >> 2) & 3, st = blk & 3;
    int t = threadIdx.x;
    const float* ib = in + (size_t)b * 65536;
    float* ob = out + (size_t)b * 65536;
    #pragma unroll
    for (int r = 0; r < 16; r++){
        int srow = st * 64 + r * 4 + (t >> 6);
        int o = ot * 64 + (t & 63);
        tile[r * 4 + (t >> 6)][t & 63] = ib[srow * 256 + o];
    }
    __syncthreads();
    #pragma unroll
    for (int r = 0; r < 16; r++){
        int o = ot * 64 + r * 4 + (t >> 6);
        int srow = st * 64 + (t & 63);
        ob[o * 256 + srow] = tile[t & 63][r * 4 + (t >> 6)];
    }
}

extern "C" void kernel_launch(void* const* d_in, const int* in_sizes, int n_in,
                              void* d_out, int out_size, void* d_ws, size_t ws_size,
                              hipStream_t stream) {
    const float* x    = (const float*)d_in[0];
    const float* w1   = (const float*)d_in[1];
    const float* w2   = (const float*)d_in[2];
    const float* g1   = (const float*)d_in[3];
    const float* b1   = (const float*)d_in[4];
    const float* g2   = (const float*)d_in[5];
    const float* b2   = (const float*)d_in[6];
    const float* s1w1 = (const float*)d_in[7];
    const float* s1w2 = (const float*)d_in[8];
    const float* s1g1 = (const float*)d_in[9];
    const float* s1b1 = (const float*)d_in[10];
    const float* s1g2 = (const float*)d_in[11];
    const float* s1b2 = (const float*)d_in[12];
    const float* s2w1 = (const float*)d_in[13];
    const float* s2w2 = (const float*)d_in[14];
    const float* s2g1 = (const float*)d_in[15];
    const float* s2b1 = (const float*)d_in[16];
    const float* s2g2 = (const float*)d_in[17];
    const float* s2b2 = (const float*)d_in[18];
    float* out = (float*)d_out;

    char* ws = (char*)d_ws;
    size_t off = 0;
    auto take = [&](size_t bytes){ size_t r = off; off += (bytes + 255) & ~(size_t)255; return r; };
    float* f_buf   = (float*)(ws + take(16u*4096u*64u*4u));      // f (B,N,64)
    float* f1_buf  = (float*)(ws + take(16u*512u*128u*4u));      // f1 (B,S1,128)
    int*   fidx1   = (int*)  (ws + take(16u*512u*4u));
    float* xyz1    = (float*)(ws + take(16u*512u*3u*4u));
    int*   fidx2   = (int*)  (ws + take(16u*256u*4u));
    float* xyz2    = (float*)(ws + take(16u*256u*3u*4u));
    int*   knn1    = (int*)  (ws + take(16u*512u*32u*4u));
    int*   knn2    = (int*)  (ws + take(16u*256u*32u*4u));
    unsigned short* wp1 = (unsigned short*)(ws + take(128u*128u*2u));
    unsigned short* wp2 = (unsigned short*)(ws + take(128u*128u*2u));
    unsigned short* wp3 = (unsigned short*)(ws + take(256u*256u*2u));
    unsigned short* wp4 = (unsigned short*)(ws + take(256u*256u*2u));
    float* stats   = (float*)(ws + take(6u*1024u*4u));
    float* ssb     = (float*)(ws + take(6u*1024u*4u));
    float* f2tmp   = (float*)(ws + take(16u*256u*256u*4u));
    char*  regA    = ws + take(67108864u);
    char*  regB    = ws + take(67108864u);
    (void)in_sizes; (void)n_in; (void)out_size; (void)ws_size;

    hipMemsetAsync(stats, 0, 6u*1024u*4u, stream);

    pack_w_kernel<128,128><<<8, 256, 0, stream>>>(s1w1, wp1);
    pack_w_kernel<128,128><<<8, 256, 0, stream>>>(s1w2, wp2);
    pack_w_kernel<256,256><<<32, 256, 0, stream>>>(s2w1, wp3);
    pack_w_kernel<256,256><<<32, 256, 0, stream>>>(s2w2, wp4);

    float* yA = (float*)regA;
    float* yB = (float*)regB;
    pc1_kernel<<<256, 256, 0, stream>>>(x, w1, yA);
    stats_bcn_kernel<64,4096><<<1024, 256, 0, stream>>>(yA, stats + 0*1024);
    bn_finalize_kernel<<<1, 256, 0, stream>>>(stats + 0*1024, g1, b1, ssb + 0*1024, 64, 1.f/65536.f);
    pc2_kernel<<<256, 256, 0, stream>>>(yA, w2, ssb + 0*1024, yB);
    stats_bcn_kernel<64,4096><<<1024, 256, 0, stream>>>(yB, stats + 1*1024);
    bn_finalize_kernel<<<1, 256, 0, stream>>>(stats + 1*1024, g2, b2, ssb + 1*1024, 64, 1.f/65536.f);
    transpose_f_kernel<<<1024, 256, 0, stream>>>(yB, ssb + 1*1024, f_buf);

    fps_kernel<4096,512,256,true><<<16, 256, 0, stream>>>(x, fidx1, xyz1);
    knn_kernel<4096,512,true><<<8192, 64, 0, stream>>>(x, xyz1, knn1);

    unsigned short* Y1 = (unsigned short*)regA;
    unsigned short* Y2 = (unsigned short*)regB;
    gemm1_kernel<64,128,512,4096><<<4096, 256, 0, stream>>>(f_buf, fidx1, knn1, (const short*)wp1, Y1, stats + 2*1024);
    bn_finalize_kernel<<<1, 256, 0, stream>>>(stats + 2*1024, s1g1, s1b1, ssb + 2*1024, 128, 1.f/262144.f);
    gemm2_kernel<128,128><<<4096, 256, 0, stream>>>(Y1, ssb + 2*1024, (const short*)wp2, Y2, stats + 3*1024);
    bn_finalize_kernel<<<1, 256, 0, stream>>>(stats + 3*1024, s1g2, s1b2, ssb + 3*1024, 128, 1.f/262144.f);
    maxk_kernel<128><<<4096, 256, 0, stream>>>(Y2, ssb + 3*1024, f1_buf);

    fps_kernel<512,256,64,false><<<16, 64, 0, stream>>>(xyz1, fidx2, xyz2);
    knn_kernel<512,256,false><<<4096, 64, 0, stream>>>(xyz1, xyz2, knn2);

    gemm1_kernel<128,256,256,512><<<2048, 256, 0, stream>>>(f1_buf, fidx2, knn2, (const short*)wp3, Y1, stats + 4*1024);
    bn_finalize_kernel<<<1, 256, 0, stream>>>(stats + 4*1024, s2g1, s2b1, ssb + 4*1024, 256, 1.f/131072.f);
    gemm2_kernel<256,256><<<2048, 256, 0, stream>>>(Y1, ssb + 4*1024, (const short*)wp4, Y2, stats + 5*1024);
    bn_finalize_kernel<<<1, 256, 0, stream>>>(stats + 5*1024, s2g2, s2b2, ssb + 5*1024, 256, 1.f/131072.f);
    maxk_kernel<256><<<4096, 256, 0, stream>>>(Y2, ssb + 5*1024, f2tmp);
    transpose_out_kernel<<<256, 256, 0, stream>>>(f2tmp, out);
}

// Round 7
// 1080.092 us; speedup vs baseline: 1.3862x; 1.1025x over previous
//
#include <hip/hip_runtime.h>

#define EPSF 1e-5f
#define NBINS 64
#define STATS_REGION 32768   // floats per stats region: NBINS * 2 * Cmax(256)

using short8  = __attribute__((ext_vector_type(8))) short;
using float4v = __attribute__((ext_vector_type(4))) float;

__device__ __forceinline__ unsigned short f2bf(float f){
    unsigned u = __float_as_uint(f);
    unsigned r = u + 0x7FFFu + ((u >> 16) & 1u);
    return (unsigned short)(r >> 16);
}
__device__ __forceinline__ float bf2f(unsigned short h){
    return __uint_as_float(((unsigned)h) << 16);
}
// monotone map: ascending float (incl. negatives) -> ascending uint
__device__ __forceinline__ unsigned monou(float f){
    unsigned u = __float_as_uint(f);
    return u ^ (((unsigned)((int)u >> 31)) | 0x80000000u);
}

// DPP-based wave64 f32 max stage: VALU latency (~8cyc) instead of ds_bpermute
// (~120cyc). old=src => masked/invalid lanes keep own value (identity for max).
template<int CTRL, int RMASK>
__device__ __forceinline__ float fmax_dpp(float x){
    int xi = __float_as_int(x);
    int yi = __builtin_amdgcn_update_dpp(xi, xi, CTRL, RMASK, 0xf, false);
    return fmaxf(x, __int_as_float(yi));
}
// full wave64 max (values >= 0, no NaN); result valid in lane 63, broadcast via readlane
__device__ __forceinline__ float wave_max_dpp(float x){
    x = fmax_dpp<0x111, 0xf>(x);  // row_shr:1
    x = fmax_dpp<0x112, 0xf>(x);  // row_shr:2
    x = fmax_dpp<0x114, 0xf>(x);  // row_shr:4
    x = fmax_dpp<0x118, 0xf>(x);  // row_shr:8  -> lane15/31/47/63 hold row maxes
    x = fmax_dpp<0x142, 0xa>(x);  // row_bcast15 -> lanes 31,63 hold half maxes
    x = fmax_dpp<0x143, 0xc>(x);  // row_bcast31 -> lane 63 holds wave max
    return __int_as_float(__builtin_amdgcn_readlane(__float_as_int(x), 63));
}

// ---------------- point_cbr stage ----------------

__global__ __launch_bounds__(256) void pc1_kernel(const float* __restrict__ x,
                                                  const float* __restrict__ w1,
                                                  float* __restrict__ y){
    __shared__ float w[192];
    int t = threadIdx.x;
    if (t < 192) w[t] = w1[t];
    __syncthreads();
    int gid = blockIdx.x * 256 + t;       // over B*N
    int b = gid >> 12;
    int n = gid & 4095;
    const float* xb = x + (size_t)b * 3 * 4096;
    float x0 = xb[n], x1 = xb[4096 + n], x2 = xb[8192 + n];
    float* yb = y + (size_t)b * 64 * 4096;
    #pragma unroll
    for (int o = 0; o < 64; o++){
        float v = x0 * w[o*3] + x1 * w[o*3+1] + x2 * w[o*3+2];
        yb[(size_t)o * 4096 + n] = v;
    }
}

template<int C, int NN>
__global__ __launch_bounds__(256) void stats_bcn_kernel(const float* __restrict__ y,
                                                        float* __restrict__ sums){
    int blk = blockIdx.x;                  // b*C + c
    int c = blk % C;
    const float* p = y + (size_t)blk * NN;
    float s = 0.f, q = 0.f;
    for (int i = threadIdx.x; i < NN; i += 256){ float v = p[i]; s += v; q += v*v; }
    for (int o = 32; o > 0; o >>= 1){ s += __shfl_down(s, o, 64); q += __shfl_down(q, o, 64); }
    __shared__ float ls[4], lq[4];
    int w = threadIdx.x >> 6;
    if ((threadIdx.x & 63) == 0){ ls[w] = s; lq[w] = q; }
    __syncthreads();
    if (threadIdx.x == 0){
        s = ls[0] + ls[1] + ls[2] + ls[3];
        q = lq[0] + lq[1] + lq[2] + lq[3];
        atomicAdd(&sums[c], s);
        atomicAdd(&sums[C + c], q);
    }
}

// reduces NB bins of [2C] partial sums
__global__ void bn_finalize_kernel(const float* __restrict__ sums,
                                   const float* __restrict__ g,
                                   const float* __restrict__ bb,
                                   float* __restrict__ ss, int C, int NB, float invCnt){
    int c = blockIdx.x * blockDim.x + threadIdx.x;
    if (c < C){
        float s = 0.f, q = 0.f;
        for (int bin = 0; bin < NB; bin++){
            s += sums[bin * 2 * C + c];
            q += sums[bin * 2 * C + C + c];
        }
        float m = s * invCnt;
        float v = q * invCnt - m * m;
        float sc = g[c] / sqrtf(v + EPSF);
        ss[c] = sc;
        ss[C + c] = bb[c] - m * sc;
    }
}

__global__ __launch_bounds__(256) void pc2_kernel(const float* __restrict__ y1,
                                                  const float* __restrict__ w2,
                                                  const float* __restrict__ ss,
                                                  float* __restrict__ y2){
    __shared__ float wt[64*64];   // wt[c*64+o] = w2[o*64+c]
    __shared__ float lss[128];
    int t = threadIdx.x;
    for (int i = t; i < 4096; i += 256){ int o = i & 63, c = i >> 6; wt[c*64+o] = w2[o*64+c]; }
    if (t < 128) lss[t] = ss[t];
    __syncthreads();
    int gid = blockIdx.x * 256 + t;
    int b = gid >> 12, n = gid & 4095;
    const float* yb = y1 + (size_t)b * 64 * 4096;
    float acc[64];
    #pragma unroll
    for (int o = 0; o < 64; o++) acc[o] = 0.f;
    for (int c = 0; c < 64; c++){
        float v = yb[(size_t)c * 4096 + n];
        v = fmaxf(v * lss[c] + lss[64 + c], 0.f);
        #pragma unroll
        for (int o = 0; o < 64; o++) acc[o] += v * wt[c*64 + o];
    }
    float* ob = y2 + (size_t)b * 64 * 4096;
    #pragma unroll
    for (int o = 0; o < 64; o++) ob[(size_t)o * 4096 + n] = acc[o];
}

// y2 (B,64,N) --bn+relu--> f (B,N,64)
__global__ __launch_bounds__(256) void transpose_f_kernel(const float* __restrict__ y2,
                                                          const float* __restrict__ ss,
                                                          float* __restrict__ f){
    __shared__ float tile[64][65];
    __shared__ float lss[128];
    int t = threadIdx.x;
    if (t < 128) lss[t] = ss[t];
    __syncthreads();
    int blk = blockIdx.x;               // b*(N/64) + ntile
    int b = blk >> 6;
    int nb = (blk & 63) * 64;
    const float* yb = y2 + (size_t)b * 64 * 4096;
    #pragma unroll
    for (int r = 0; r < 16; r++){
        int c = r * 4 + (t >> 6);
        int n = t & 63;
        float v = yb[(size_t)c * 4096 + nb + n];
        tile[c][n] = fmaxf(v * lss[c] + lss[64 + c], 0.f);
    }
    __syncthreads();
    float* fb = f + (size_t)b * 4096 * 64;
    #pragma unroll
    for (int r = 0; r < 16; r++){
        int n = r * 4 + (t >> 6);
        int c = t & 63;
        fb[(size_t)(nb + n) * 64 + c] = tile[c][n];
    }
}

// ---------------- FPS ----------------
// R6 structure: DPP wave argmax + ballot/ffs/readlane tie-break (325us measured).
template<int NP, int SO, int TPB, bool STRIDED>
__global__ __launch_bounds__(TPB) void fps_kernel(const float* __restrict__ coords,
                                                  int* __restrict__ fidx,
                                                  float* __restrict__ xyz_out){
    __shared__ float lx[NP], ly[NP], lz[NP];
    constexpr int W = TPB / 64;
    __shared__ unsigned long long red[2][W];
    const int b = blockIdx.x, t = threadIdx.x;
    constexpr int P = NP / TPB;
    const float* cb = coords + (size_t)b * 3 * NP;
    float px[P], py[P], pz[P], dist[P];
    // coalesced staging into LDS
    #pragma unroll
    for (int i = 0; i < P; i++){
        int n = i * TPB + t;
        float X, Y, Z;
        if (STRIDED){ X = cb[n]; Y = cb[NP + n]; Z = cb[2*NP + n]; }
        else        { X = cb[n*3]; Y = cb[n*3+1]; Z = cb[n*3+2]; }
        lx[n] = X; ly[n] = Y; lz[n] = Z;
    }
    __syncthreads();
    // lane-major register copy: this thread owns points [t*P, t*P+P)
    #pragma unroll
    for (int i = 0; i < P; i++){
        int n = t * P + i;
        px[i] = lx[n]; py[i] = ly[n]; pz[i] = lz[n];
        dist[i] = 1e10f;
    }
    int cur = 0;
    for (int it = 0; it < SO; ++it){
        if (t == 0){
            fidx[b * SO + it] = cur;
            float* xo = xyz_out + ((size_t)b * SO + it) * 3;
            xo[0] = lx[cur]; xo[1] = ly[cur]; xo[2] = lz[cur];
        }
        float cx = lx[cur], cy = ly[cur], cz = lz[cur];
        float bd = -1.f;
        int bn = 0;
        {
            #pragma clang fp contract(off)
            #pragma unroll
            for (int i = 0; i < P; i++){
                float dx = px[i] - cx, dy = py[i] - cy, dz = pz[i] - cz;
                float d = (dx*dx + dy*dy) + dz*dz;   // match np: no fma, ((x+y)+z)
                float nd = fminf(dist[i], d);
                dist[i] = nd;
                if (nd > bd){ bd = nd; bn = t * P + i; }  // strict >: lowest i (= lowest n)
            }
        }
        // wave max via DPP (bd >= 0 after loop), then exact lowest-n tie-break
        float wm = wave_max_dpp(bd);
        unsigned long long msk = __ballot(bd == wm);
        int wl = (int)(__ffsll(msk) - 1);
        int n_w = __builtin_amdgcn_readlane(bn, wl);
        if constexpr (W == 1){
            cur = n_w;
        } else {
            int par = it & 1;
            if ((t & 63) == 0){
                red[par][t >> 6] = ((unsigned long long)__float_as_uint(wm) << 32)
                                 | (unsigned)(0xFFFFFFFFu - (unsigned)n_w);
            }
            __syncthreads();
            unsigned long long best = red[par][0];
            #pragma unroll
            for (int j = 1; j < W; j++){
                unsigned long long v = red[par][j];
                best = best > v ? best : v;
            }
            cur = (int)(0xFFFFFFFFu - (unsigned)(best & 0xFFFFFFFFull));
        }
    }
}

// ---------------- kNN (exact top-32 by (dist, idx)) ----------------

template<int NC, int SO, bool STRIDED>
__global__ __launch_bounds__(64) void knn_kernel(const float* __restrict__ coords,
                                                 const float* __restrict__ samp,
                                                 int* __restrict__ knno){
    const int blk = blockIdx.x;
    const int b = blk / SO, s = blk % SO;
    const int lane = threadIdx.x;
    const float* cb = coords + (size_t)b * 3 * NC;
    const float* a = samp + ((size_t)b * SO + s) * 3;
    float ax = a[0], ay = a[1], az = a[2];
    float asq = ax*ax + ay*ay + az*az;
    constexpr int J = NC / 64;
    unsigned long long t8[8];
    #pragma unroll
    for (int i = 0; i < 8; i++) t8[i] = ~0ULL;
    for (int j = 0; j < J; j++){
        int n = j * 64 + lane;
        float bx, by, bz;
        if (STRIDED){ bx = cb[n]; by = cb[NC + n]; bz = cb[2*NC + n]; }
        else        { bx = cb[n*3]; by = cb[n*3+1]; bz = cb[n*3+2]; }
        float bsq = bx*bx + by*by + bz*bz;
        float dot = ax*bx + ay*by + az*bz;
        float d = (asq + bsq) - 2.0f * dot;       // reference's formula
        unsigned long long key = ((unsigned long long)monou(d) << 32) | (unsigned)n;
        if (key < t8[7]){
            t8[7] = key;
            #pragma unroll
            for (int i = 6; i >= 0; i--){
                if (t8[i] > t8[i+1]){ unsigned long long tm = t8[i]; t8[i] = t8[i+1]; t8[i+1] = tm; }
            }
        }
    }
    unsigned long long cur = t8[0];
    int myout = 0;
    bool bad = false;
    int popped = 0;
    for (int r = 0; r < 32; r++){
        unsigned long long m = cur;
        #pragma unroll
        for (int o2 = 32; o2 > 0; o2 >>= 1){
            unsigned long long v = __shfl_xor(m, o2, 64);
            m = m < v ? m : v;
        }
        if (lane == r) myout = (int)(unsigned)(m & 0xFFFFFFFFull);
        if (cur == m){
            #pragma unroll
            for (int i = 0; i < 7; i++) t8[i] = t8[i+1];
            t8[7] = ~0ULL;
            cur = t8[0];
            popped++;
            if (J > 8 && popped == 8 && r < 31) bad = true;
        }
    }
    if (__any(bad)){
        // exact fallback: ascending total-order scan (keys are unique)
        unsigned long long last = 0;
        for (int r = 0; r < 32; r++){
            unsigned long long mk = ~0ULL;
            for (int j = 0; j < J; j++){
                int n = j * 64 + lane;
                float bx, by, bz;
                if (STRIDED){ bx = cb[n]; by = cb[NC + n]; bz = cb[2*NC + n]; }
                else        { bx = cb[n*3]; by = cb[n*3+1]; bz = cb[n*3+2]; }
                float bsq = bx*bx + by*by + bz*bz;
                float dot = ax*bx + ay*by + az*bz;
                float d = (asq + bsq) - 2.0f * dot;
                unsigned long long key = ((unsigned long long)monou(d) << 32) | (unsigned)n;
                if (key > last && key < mk) mk = key;
            }
            unsigned long long m = mk;
            #pragma unroll
            for (int o2 = 32; o2 > 0; o2 >>= 1){
                unsigned long long v = __shfl_xor(m, o2, 64);
                m = m < v ? m : v;
            }
            if (lane == r) myout = (int)(unsigned)(m & 0xFFFFFFFFull);
            last = m;
        }
    }
    if (lane < 32) knno[((size_t)b * SO + s) * 32 + lane] = myout;
}

// ---------------- MFMA grouped MLP ----------------

template<int O, int D>
__global__ __launch_bounds__(256) void pack_w_kernel(const float* __restrict__ w,
                                                     unsigned short* __restrict__ pk){
    int tid = blockIdx.x * 256 + threadIdx.x;
    constexpr int CH = D / 32;
    constexpr int TOT = (O/16) * CH * 64;
    if (tid >= TOT) return;
    int lane = tid & 63;
    int fc = tid >> 6;
    int ch = fc % CH;
    int ot = fc / CH;
    int o  = ot * 16 + (lane & 15);
    int kb = ch * 32 + (lane >> 4) * 8;
    #pragma unroll
    for (int j = 0; j < 8; j++) pk[(size_t)tid * 8 + j] = f2bf(w[(size_t)o * D + kb + j]);
}

template<int D, int O>
__device__ __forceinline__ void mfma_compute_store(const short* A, const short* wp,
                                                   unsigned short* Y, float* lsum, float* lsq,
                                                   int blk, int t){
    constexpr int RS = D + 8;
    constexpr int CH = D / 32;
    constexpr int OT = O / 16;
    constexpr int OPW = OT / 4;
    int lane = t & 63, wv = t >> 6;
    int col = lane & 15, quad = lane >> 4;
    for (int oi = 0; oi < OPW; ++oi){
        int ot = wv * OPW + oi;
        for (int mt = 0; mt < 4; ++mt){
            float4v acc = {0.f, 0.f, 0.f, 0.f};
            #pragma unroll
            for (int ch = 0; ch < CH; ++ch){
                short8 a  = *(const short8*)(A + (mt*16 + col) * RS + ch*32 + quad*8);
                short8 bf = *(const short8*)(wp + ((size_t)(ot*CH + ch) * 64 + lane) * 8);
                acc = __builtin_amdgcn_mfma_f32_16x16x32_bf16(a, bf, acc, 0, 0, 0);
            }
            float s4 = 0.f, q4 = 0.f;
            size_t rowbase = (size_t)blk * 64 + mt * 16 + quad * 4;
            #pragma unroll
            for (int r = 0; r < 4; r++){
                float v = acc[r];
                s4 += v; q4 += v * v;
                Y[(rowbase + r) * O + ot * 16 + col] = f2bf(v);
            }
            s4 += __shfl_xor(s4, 16, 64); s4 += __shfl_xor(s4, 32, 64);
            q4 += __shfl_xor(q4, 16, 64); q4 += __shfl_xor(q4, 32, 64);
            if (quad == 0){ lsum[ot*16 + col] += s4; lsq[ot*16 + col] += q4; }
        }
    }
}

// layer1: gather + [f_nb - f_c | f_c] -> bf16 LDS -> MFMA, store Y bf16 + stats
template<int DH, int O, int S, int NPTS>
__global__ __launch_bounds__(256) void gemm1_kernel(const float* __restrict__ fsrc,
                                                    const int* __restrict__ fidx,
                                                    const int* __restrict__ knn,
                                                    const short* __restrict__ wp,
                                                    unsigned short* __restrict__ Y,
                                                    float* __restrict__ sums){
    constexpr int D = 2 * DH;
    constexpr int RS = D + 8;
    __shared__ __align__(16) short A[64 * RS];
    __shared__ float lsum[O], lsq[O];
    int t = threadIdx.x;
    for (int i = t; i < O; i += 256){ lsum[i] = 0.f; lsq[i] = 0.f; }
    int blk = blockIdx.x;
    for (int g = 0; g < 2; ++g){
        int gid = blk * 2 + g;
        int b = gid / S;
        int cidx = fidx[gid];
        const float* fc = fsrc + ((size_t)b * NPTS + cidx) * DH;
        int kk = t >> 3;
        int p  = t & 7;
        int nb = knn[(size_t)gid * 32 + kk];
        const float* fn = fsrc + ((size_t)b * NPTS + nb) * DH;
        constexpr int E = D / 8;
        int d0 = p * E;
        short* row = A + (g * 32 + kk) * RS;
        #pragma unroll
        for (int e = 0; e < E; e++){
            int d = d0 + e;
            float v = (d < DH) ? (fn[d] - fc[d]) : fc[d - DH];
            row[d] = (short)f2bf(v);
        }
    }
    __syncthreads();
    mfma_compute_store<D, O>(A, wp, Y, lsum, lsq, blk, t);
    __syncthreads();
    // binned global accumulation: contention per address = gridDim/NBINS
    float* dst = sums + (size_t)(blk & (NBINS - 1)) * 2 * O;
    for (int i = t; i < O; i += 256){
        atomicAdd(&dst[i], lsum[i]);
        atomicAdd(&dst[O + i], lsq[i]);
    }
}

// layer2: bn+relu(Yin) -> bf16 LDS -> MFMA, store Y bf16 + stats
template<int D, int O>
__global__ __launch_bounds__(256) void gemm2_kernel(const unsigned short* __restrict__ Yin,
                                                    const float* __restrict__ ss,
                                                    const short* __restrict__ wp,
                                                    unsigned short* __restrict__ Y,
                                                    float* __restrict__ sums){
    constexpr int RS = D + 8;
    __shared__ __align__(16) short A[64 * RS];
    __shared__ float lsum[O], lsq[O];
    __shared__ float lss[2 * D];
    int t = threadIdx.x;
    for (int i = t; i < O; i += 256){ lsum[i] = 0.f; lsq[i] = 0.f; }
    for (int i = t; i < 2*D; i += 256) lss[i] = ss[i];
    __syncthreads();
    int blk = blockIdx.x;
    {
        int row = t >> 2;
        int d0 = (t & 3) * (D / 4);
        const unsigned short* src = Yin + ((size_t)blk * 64 + row) * D + d0;
        short* dst = A + row * RS + d0;
        #pragma unroll
        for (int e = 0; e < D/4; e++){
            float v = bf2f(src[e]);
            int d = d0 + e;
            v = fmaxf(v * lss[d] + lss[D + d], 0.f);
            dst[e] = (short)f2bf(v);
        }
    }
    __syncthreads();
    mfma_compute_store<D, O>(A, wp, Y, lsum, lsq, blk, t);
    __syncthreads();
    float* dst = sums + (size_t)(blk & (NBINS - 1)) * 2 * O;
    for (int i = t; i < O; i += 256){
        atomicAdd(&dst[i], lsum[i]);
        atomicAdd(&dst[O + i], lsq[i]);
    }
}

template<int O>
__global__ __launch_bounds__(256) void maxk_kernel(const unsigned short* __restrict__ Y,
                                                   const float* __restrict__ ss,
                                                   float* __restrict__ out){
    int gid = blockIdx.x * 256 + threadIdx.x;
    int o = gid % O;
    int r = gid / O;
    float sc = ss[o], sh = ss[O + o];
    const unsigned short* p = Y + (size_t)r * 32 * O + o;
    float m = -1e30f;
    #pragma unroll 8
    for (int k = 0; k < 32; k++){
        float v = bf2f(p[(size_t)k * O]);
        m = fmaxf(m, v * sc + sh);
    }
    out[gid] = fmaxf(m, 0.f);
}

// (B,256s,256o) -> (B,256o,256s)
__global__ __launch_bounds__(256) void transpose_out_kernel(const float* __restrict__ in,
                                                            float* __restrict__ out){
    __shared__ float tile[64][65];
    int blk = blockIdx.x;
    int b = blk >> 4;
    int ot = (blk >> 2) & 3, st = blk & 3;
    int t = threadIdx.x;
    const float* ib = in + (size_t)b * 65536;
    float* ob = out + (size_t)b * 65536;
    #pragma unroll
    for (int r = 0; r < 16; r++){
        int srow = st * 64 + r * 4 + (t >> 6);
        int o = ot * 64 + (t & 63);
        tile[r * 4 + (t >> 6)][t & 63] = ib[srow * 256 + o];
    }
    __syncthreads();
    #pragma unroll
    for (int r = 0; r < 16; r++){
        int o = ot * 64 + r * 4 + (t >> 6);
        int srow = st * 64 + (t & 63);
        ob[o * 256 + srow] = tile[t & 63][r * 4 + (t >> 6)];
    }
}

extern "C" void kernel_launch(void* const* d_in, const int* in_sizes, int n_in,
                              void* d_out, int out_size, void* d_ws, size_t ws_size,
                              hipStream_t stream) {
    const float* x    = (const float*)d_in[0];
    const float* w1   = (const float*)d_in[1];
    const float* w2   = (const float*)d_in[2];
    const float* g1   = (const float*)d_in[3];
    const float* b1   = (const float*)d_in[4];
    const float* g2   = (const float*)d_in[5];
    const float* b2   = (const float*)d_in[6];
    const float* s1w1 = (const float*)d_in[7];
    const float* s1w2 = (const float*)d_in[8];
    const float* s1g1 = (const float*)d_in[9];
    const float* s1b1 = (const float*)d_in[10];
    const float* s1g2 = (const float*)d_in[11];
    const float* s1b2 = (const float*)d_in[12];
    const float* s2w1 = (const float*)d_in[13];
    const float* s2w2 = (const float*)d_in[14];
    const float* s2g1 = (const float*)d_in[15];
    const float* s2b1 = (const float*)d_in[16];
    const float* s2g2 = (const float*)d_in[17];
    const float* s2b2 = (const float*)d_in[18];
    float* out = (float*)d_out;

    char* ws = (char*)d_ws;
    size_t off = 0;
    auto take = [&](size_t bytes){ size_t r = off; off += (bytes + 255) & ~(size_t)255; return r; };
    float* f_buf   = (float*)(ws + take(16u*4096u*64u*4u));      // f (B,N,64)
    float* f1_buf  = (float*)(ws + take(16u*512u*128u*4u));      // f1 (B,S1,128)
    int*   fidx1   = (int*)  (ws + take(16u*512u*4u));
    float* xyz1    = (float*)(ws + take(16u*512u*3u*4u));
    int*   fidx2   = (int*)  (ws + take(16u*256u*4u));
    float* xyz2    = (float*)(ws + take(16u*256u*3u*4u));
    int*   knn1    = (int*)  (ws + take(16u*512u*32u*4u));
    int*   knn2    = (int*)  (ws + take(16u*256u*32u*4u));
    unsigned short* wp1 = (unsigned short*)(ws + take(128u*128u*2u));
    unsigned short* wp2 = (unsigned short*)(ws + take(128u*128u*2u));
    unsigned short* wp3 = (unsigned short*)(ws + take(256u*256u*2u));
    unsigned short* wp4 = (unsigned short*)(ws + take(256u*256u*2u));
    float* stats   = (float*)(ws + take(6u*STATS_REGION*4u));    // 6 regions x 64 bins x 2*Cmax
    float* ssb     = (float*)(ws + take(6u*1024u*4u));
    float* f2tmp   = (float*)(ws + take(16u*256u*256u*4u));
    char*  regA    = ws + take(67108864u);
    char*  regB    = ws + take(67108864u);
    (void)in_sizes; (void)n_in; (void)out_size; (void)ws_size;

    hipMemsetAsync(stats, 0, 6u*STATS_REGION*4u, stream);

    pack_w_kernel<128,128><<<8, 256, 0, stream>>>(s1w1, wp1);
    pack_w_kernel<128,128><<<8, 256, 0, stream>>>(s1w2, wp2);
    pack_w_kernel<256,256><<<32, 256, 0, stream>>>(s2w1, wp3);
    pack_w_kernel<256,256><<<32, 256, 0, stream>>>(s2w2, wp4);

    float* yA = (float*)regA;
    float* yB = (float*)regB;
    pc1_kernel<<<256, 256, 0, stream>>>(x, w1, yA);
    stats_bcn_kernel<64,4096><<<1024, 256, 0, stream>>>(yA, stats + 0*STATS_REGION);
    bn_finalize_kernel<<<1, 256, 0, stream>>>(stats + 0*STATS_REGION, g1, b1, ssb + 0*1024, 64, 1, 1.f/65536.f);
    pc2_kernel<<<256, 256, 0, stream>>>(yA, w2, ssb + 0*1024, yB);
    stats_bcn_kernel<64,4096><<<1024, 256, 0, stream>>>(yB, stats + 1*STATS_REGION);
    bn_finalize_kernel<<<1, 256, 0, stream>>>(stats + 1*STATS_REGION, g2, b2, ssb + 1*1024, 64, 1, 1.f/65536.f);
    transpose_f_kernel<<<1024, 256, 0, stream>>>(yB, ssb + 1*1024, f_buf);

    fps_kernel<4096,512,256,true><<<16, 256, 0, stream>>>(x, fidx1, xyz1);
    knn_kernel<4096,512,true><<<8192, 64, 0, stream>>>(x, xyz1, knn1);

    unsigned short* Y1 = (unsigned short*)regA;
    unsigned short* Y2 = (unsigned short*)regB;
    gemm1_kernel<64,128,512,4096><<<4096, 256, 0, stream>>>(f_buf, fidx1, knn1, (const short*)wp1, Y1, stats + 2*STATS_REGION);
    bn_finalize_kernel<<<1, 256, 0, stream>>>(stats + 2*STATS_REGION, s1g1, s1b1, ssb + 2*1024, 128, NBINS, 1.f/262144.f);
    gemm2_kernel<128,128><<<4096, 256, 0, stream>>>(Y1, ssb + 2*1024, (const short*)wp2, Y2, stats + 3*STATS_REGION);
    bn_finalize_kernel<<<1, 256, 0, stream>>>(stats + 3*STATS_REGION, s1g2, s1b2, ssb + 3*1024, 128, NBINS, 1.f/262144.f);
    maxk_kernel<128><<<4096, 256, 0, stream>>>(Y2, ssb + 3*1024, f1_buf);

    fps_kernel<512,256,64,false><<<16, 64, 0, stream>>>(xyz1, fidx2, xyz2);
    knn_kernel<512,256,false><<<4096, 64, 0, stream>>>(xyz1, xyz2, knn2);

    gemm1_kernel<128,256,256,512><<<2048, 256, 0, stream>>>(f1_buf, fidx2, knn2, (const short*)wp3, Y1, stats + 4*STATS_REGION);
    bn_finalize_kernel<<<1, 256, 0, stream>>>(stats + 4*STATS_REGION, s2g1, s2b1, ssb + 4*1024, 256, NBINS, 1.f/131072.f);
    gemm2_kernel<256,256><<<2048, 256, 0, stream>>>(Y1, ssb + 4*1024, (const short*)wp4, Y2, stats + 5*STATS_REGION);
    bn_finalize_kernel<<<1, 256, 0, stream>>>(stats + 5*STATS_REGION, s2g2, s2b2, ssb + 5*1024, 256, NBINS, 1.f/131072.f);
    maxk_kernel<256><<<4096, 256, 0, stream>>>(Y2, ssb + 5*1024, f2tmp);
    transpose_out_kernel<<<256, 256, 0, stream>>>(f2tmp, out);
}